// Round 12
// baseline (328.501 us; speedup 1.0000x reference)
//
#include <hip/hip_runtime.h>
#include <cstddef>
#include <cstdint>

// ---------------------------------------------------------------------------
// attention_net_noc: pointer-network decode step.
// R15 = R14 (282.5 us best) + query-independent matvec precompute:
//   logit_i = tanh(qk_i + (Wr@e)_i) . V_i -- the Wr@e term doesn't depend on
//   the query. Sweep A (which has e in registers) computes and caches
//   wrB = ja_Wr@e (jobs) and wrD = ma_Wr@e (machines). B and D then read the
//   SAME byte count as before but skip their 512-slot matvec (750->~250
//   VALU slots/thread). C is unchanged (reusing its wr would double C's
//   read bytes). A pays +512 pk-slots and +96 MB of streaming stores.
// Three tiers by workspace size: 2=full (e+wr, 192MB), 1=e-only (=R14,
// 96MB), 0=none. Ledger: sync escapes dead (R8/R11), prologue folding dead
// (R12), A-repack/NT dead (R13).
// ---------------------------------------------------------------------------

constexpr int NJ = 1000000;
constexpr int NM = 500000;
constexpr float NEGV = -1e8f;

constexpr int BLK = 256;
constexpr int ROWS_PER_BLK = 1024;           // 4 adjacent rows per thread
constexpr int GB_J = (NJ + ROWS_PER_BLK - 1) / ROWS_PER_BLK;   // 977
constexpr int GB_M = (NM + ROWS_PER_BLK - 1) / ROWS_PER_BLK;   // 489
constexpr int GB_TOT = GB_J + GB_M;                             // 1466
constexpr int EBLK = ROWS_PER_BLK * 16;                         // 16384 floats/tile

// ---- workspace layout (float offsets from start of d_ws) ----
constexpr int S_QKJA = 0;    // 16: ja_Wq@g1 + ja_bq
constexpr int S_QK2J = 16;   // 16: aj_Wq@e_js + aj_bq
constexpr int S_QK2M = 32;   // 16: am_Wq@e_js + am_bq
constexpr int S_EJS  = 48;   // 16: E_j[sel_j]
constexpr int S_QKMA = 64;   // 16: ma_Wq@g2 + ma_bq
constexpr int S_LOGPJ = 80;
constexpr int S_SELJ  = 81;  // stored as float (exact, < 2^24)
constexpr int P1J = 128;                       // GB_J*17 glimpse partials (l, s[16])
constexpr int P1M = P1J + GB_J * 17;
constexpr int P2V = P1M + GB_M * 17;           // GB_J argmax vals (mlogits reuses)
constexpr int P2I = P2V + GB_J;
constexpr int P2L = P2I + GB_J;
constexpr size_t E_OFF = 65536;                // float offset of E cache tiles
static_assert(P2L + GB_J <= (int)E_OFF, "partials overflow into E cache");
static_assert(NJ % 4 == 0 && NM % 4 == 0, "4-row packing needs n % 4 == 0");

typedef float v2f __attribute__((ext_vector_type(2)));

struct Params {
    const float *jobs, *machines;
    const int *mask;
    const float *jW1, *jb1, *jW2, *jb2;
    const float *mW1, *mb1, *mW2, *mb2;
    const float *aj_Wq, *aj_bq, *aj_Wr, *aj_V;
    const float *am_Wq, *am_bq, *am_Wr, *am_V;
    const float *ja_Wq, *ja_bq, *ja_Wr, *ja_V;
    const float *ma_Wq, *ma_bq, *ma_Wr, *ma_V;
    const float *g1W, *g1b, *g2W, *g2b, *last_j;
    float *S;        // smalls + partials (in ws)
    float *Ej, *Em;  // embedding cache tiles (tier >= 1)
    float *Wj, *Wm;  // ja_Wr@e / ma_Wr@e caches (tier == 2)
    float *out;
};

// ---------------------------------------------------------------------------
// device helpers (verified R9-R14 versions)
// ---------------------------------------------------------------------------

__device__ __forceinline__ float fast_tanh(float x) {
    float e = __builtin_amdgcn_exp2f(x * 2.8853900817779268f);  // 2/ln2
    float r = __builtin_amdgcn_rcpf(e + 1.0f);
    return fmaf(-2.0f, r, 1.0f);
}

__device__ __forceinline__ v2f vbc(float a) { v2f r; r.x = a; r.y = a; return r; }

__device__ __forceinline__ v2f vfma(float w, v2f b, v2f c) {
    return __builtin_elementwise_fma(vbc(w), b, c);
}
__device__ __forceinline__ v2f vfma2(v2f a, v2f b, v2f c) {
    return __builtin_elementwise_fma(a, b, c);
}
__device__ __forceinline__ v2f vtanh(v2f a) {
    v2f r; r.x = fast_tanh(a.x); r.y = fast_tanh(a.y); return r;
}

__device__ __forceinline__ void load16(const float* __restrict__ X, size_t r, float (&x)[16]) {
    const float4* p4 = reinterpret_cast<const float4*>(X) + r * 4;
    float4 a = p4[0], b = p4[1], c = p4[2], d = p4[3];
    x[0]=a.x; x[1]=a.y; x[2]=a.z; x[3]=a.w;
    x[4]=b.x; x[5]=b.y; x[6]=b.z; x[7]=b.w;
    x[8]=c.x; x[9]=c.y; x[10]=c.z; x[11]=c.w;
    x[12]=d.x; x[13]=d.y; x[14]=d.z; x[15]=d.w;
}

__device__ __forceinline__ void load16_v2(const float* __restrict__ X, size_t rA, size_t rB,
                                          v2f (&x)[16]) {
    float a[16], b[16];
    load16(X, rA, a);
    load16(X, rB, b);
#pragma unroll
    for (int k = 0; k < 16; ++k) { x[k].x = a[k]; x[k].y = b[k]; }
}

// tile for 4 rows/thread: [8 kp][2 pairs][256 threads * float4]
__device__ __forceinline__ void ecache_store4(float* __restrict__ Eb, int t,
                                              const v2f (&e0)[16], const v2f (&e1)[16]) {
    float4* p4 = reinterpret_cast<float4*>(Eb);
#pragma unroll
    for (int kp = 0; kp < 8; ++kp) {
        p4[kp * 512 + t]       = make_float4(e0[2*kp].x, e0[2*kp].y, e0[2*kp+1].x, e0[2*kp+1].y);
        p4[kp * 512 + 256 + t] = make_float4(e1[2*kp].x, e1[2*kp].y, e1[2*kp+1].x, e1[2*kp+1].y);
    }
}
__device__ __forceinline__ void ecache_load4(const float* __restrict__ Eb, int t,
                                             v2f (&e0)[16], v2f (&e1)[16]) {
    const float4* p4 = reinterpret_cast<const float4*>(Eb);
#pragma unroll
    for (int kp = 0; kp < 8; ++kp) {
        float4 q0 = p4[kp * 512 + t];
        float4 q1 = p4[kp * 512 + 256 + t];
        e0[2*kp].x = q0.x;   e0[2*kp].y = q0.y;
        e0[2*kp+1].x = q0.z; e0[2*kp+1].y = q0.w;
        e1[2*kp].x = q1.x;   e1[2*kp].y = q1.y;
        e1[2*kp+1].x = q1.z; e1[2*kp+1].y = q1.w;
    }
}

__device__ __forceinline__ void emb16_v2(const v2f (&x)[16],
                                         const float* __restrict__ W1, const float* __restrict__ b1,
                                         const float* __restrict__ W2, const float* __restrict__ b2,
                                         v2f (&e)[16]) {
    v2f h[16];
#pragma unroll
    for (int i = 0; i < 16; ++i) {
        v2f a = vbc(b1[i]);
#pragma unroll
        for (int k = 0; k < 16; ++k) a = vfma(W1[i * 16 + k], x[k], a);
        h[i] = vtanh(a);
    }
#pragma unroll
    for (int i = 0; i < 16; ++i) {
        v2f a = vbc(b2[i]);
#pragma unroll
        for (int k = 0; k < 16; ++k) a = vfma(W2[i * 16 + k], h[k], a);
        e[i] = vtanh(a);
    }
}

// full logit: tanh(qk + Wr @ e) . V
__device__ __forceinline__ v2f att_logit_v2(const v2f (&e)[16], const float (&qk)[16],
                                            const float* __restrict__ Wr,
                                            const float* __restrict__ V) {
    v2f acc = vbc(0.0f);
#pragma unroll
    for (int i = 0; i < 16; ++i) {
        v2f r = vbc(qk[i]);
#pragma unroll
        for (int k = 0; k < 16; ++k) r = vfma(Wr[i * 16 + k], e[k], r);
        acc = vfma2(vbc(V[i]), vtanh(r), acc);
    }
    return acc;
}

// precomputed-wr logit: tanh(qk + wr) . V  (~1/3 the slots of att_logit_v2)
__device__ __forceinline__ v2f att_logit_pre(const v2f (&wr)[16], const float (&qk)[16],
                                             const float* __restrict__ V) {
    v2f acc = vbc(0.0f);
#pragma unroll
    for (int i = 0; i < 16; ++i)
        acc = vfma2(vbc(V[i]), vtanh(vbc(qk[i]) + wr[i]), acc);
    return acc;
}

// wr = Wr @ e (no bias), two packed pairs
__device__ __forceinline__ void wr_mv2(const v2f (&e0)[16], const v2f (&e1)[16],
                                       const float* __restrict__ Wr,
                                       v2f (&w0)[16], v2f (&w1)[16]) {
#pragma unroll
    for (int i = 0; i < 16; ++i) {
        v2f a = vbc(0.0f), b = vbc(0.0f);
#pragma unroll
        for (int k = 0; k < 16; ++k) {
            a = vfma(Wr[i * 16 + k], e0[k], a);
            b = vfma(Wr[i * 16 + k], e1[k], b);
        }
        w0[i] = a; w1[i] = b;
    }
}

__device__ __forceinline__ float wave_reduce_sum(float v) {
#pragma unroll
    for (int off = 32; off > 0; off >>= 1) v += __shfl_xor(v, off, 64);
    return v;
}

__device__ __forceinline__ void wave_reduce_argmax(float &v, int &idx) {
#pragma unroll
    for (int off = 32; off > 0; off >>= 1) {
        float ov = __shfl_xor(v, off, 64);
        int oi = __shfl_xor(idx, off, 64);
        if (ov > v || (ov == v && oi < idx)) { v = ov; idx = oi; }
    }
}

__device__ __forceinline__ float block_sum(float v) {
    __shared__ float sm[4];
    v = wave_reduce_sum(v);
    __syncthreads();
    if ((threadIdx.x & 63) == 0) sm[threadIdx.x >> 6] = v;
    __syncthreads();
    return sm[0] + sm[1] + sm[2] + sm[3];
}

__device__ __forceinline__ void block_argmax(float &v, int &i) {
    __shared__ float sv[4];
    __shared__ int si[4];
    wave_reduce_argmax(v, i);
    __syncthreads();
    if ((threadIdx.x & 63) == 0) { sv[threadIdx.x >> 6] = v; si[threadIdx.x >> 6] = i; }
    __syncthreads();
    float bv = sv[0]; int bi = si[0];
#pragma unroll
    for (int k = 1; k < 4; ++k)
        if (sv[k] > bv || (sv[k] == bv && si[k] < bi)) { bv = sv[k]; bi = si[k]; }
    v = bv; i = bi;
}

// Block-reduce (l, s[16]) -> dst[17]. dst[0]=l, dst[1+j]=s[j]. Verified R7-R14.
__device__ __forceinline__ void block_sum17(float l, const float (&s)[16], float* dst) {
    const int lane = threadIdx.x & 63;
    float c[8];
#pragma unroll
    for (int j = 0; j < 8; ++j) {          // xor 1: 16 -> 8
        const bool hi = lane & 1;
        float t = __shfl_xor(hi ? s[j] : s[j + 8], 1, 64);
        c[j] = (hi ? s[j + 8] : s[j]) + t;
    }
    float d[4];
#pragma unroll
    for (int j = 0; j < 4; ++j) {          // xor 2: 8 -> 4
        const bool hi = lane & 2;
        float t = __shfl_xor(hi ? c[j] : c[j + 4], 2, 64);
        d[j] = (hi ? c[j + 4] : c[j]) + t;
    }
    float e2[2];
#pragma unroll
    for (int j = 0; j < 2; ++j) {          // xor 4: 4 -> 2
        const bool hi = lane & 4;
        float t = __shfl_xor(hi ? d[j] : d[j + 2], 4, 64);
        e2[j] = (hi ? d[j + 2] : d[j]) + t;
    }
    float f;
    {                                       // xor 8: 2 -> 1
        const bool hi = lane & 8;
        float t = __shfl_xor(hi ? e2[0] : e2[1], 8, 64);
        f = (hi ? e2[1] : e2[0]) + t;
    }
    f += __shfl_xor(f, 16, 64);
    f += __shfl_xor(f, 32, 64);
#pragma unroll
    for (int off = 32; off > 0; off >>= 1) l += __shfl_xor(l, off, 64);

    const int idx = ((lane & 1) << 3) | ((lane & 2) << 1) | ((lane & 4) >> 1) | ((lane & 8) >> 3);
    __shared__ float red[4][17];
    const int w = threadIdx.x >> 6;
    __syncthreads();                        // guard reuse across successive calls
    if (lane < 16) red[w][1 + idx] = f;
    if (lane == 0) red[w][0] = l;
    __syncthreads();
    if (threadIdx.x < 17)
        dst[threadIdx.x] = red[0][threadIdx.x] + red[1][threadIdx.x] + red[2][threadIdx.x] + red[3][threadIdx.x];
}

// weighted sum of 4 rows: s[i] = w01 . e0[i] + w23 . e1[i]
__device__ __forceinline__ void wsum4(const v2f (&e0)[16], const v2f (&e1)[16],
                                      v2f w01, v2f w23, float (&s)[16]) {
#pragma unroll
    for (int i = 0; i < 16; ++i) {
        v2f t = vfma2(w23, e1[i], w01 * e0[i]);
        s[i] = t.x + t.y;
    }
}

// ---------------------------------------------------------------------------
// K1: embeddings (TIER>=1: cache e; TIER==2: also cache ja_Wr@e / ma_Wr@e)
// + glimpse-1 partials. Rows (4t..4t+3). blocks [0,GB_J)=jobs, rest machines.
// ---------------------------------------------------------------------------
template <int TIER>
__global__ __launch_bounds__(BLK) void k_emb_g1(Params p) {
    const bool isJob = blockIdx.x < GB_J;
    const float* X  = isJob ? p.jobs : p.machines;
    const float* W1 = isJob ? p.jW1 : p.mW1;
    const float* b1 = isJob ? p.jb1 : p.mb1;
    const float* W2 = isJob ? p.jW2 : p.mW2;
    const float* b2 = isJob ? p.jb2 : p.mb2;
    const float* Wr = isJob ? p.aj_Wr : p.am_Wr;
    const float* V  = isJob ? p.aj_V  : p.am_V;
    const int n  = isJob ? NJ : NM;
    const int b0 = isJob ? (int)blockIdx.x : (int)blockIdx.x - GB_J;

    const int r0 = b0 * ROWS_PER_BLK + 4 * (int)threadIdx.x;
    const bool v = r0 < n;
    const size_t a0 = v ? (size_t)r0 : 0;
    const size_t d  = v ? 1 : 0;

    // issue all 16 global loads first (latency overlaps the qk prologue)
    v2f x0[16], x1[16];
    load16_v2(X, a0, a0 + d, x0);
    load16_v2(X, a0 + 2 * d, a0 + 3 * d, x1);

    __shared__ float qks[16];
    if (threadIdx.x < 16) {
        const float* Wq = isJob ? p.aj_Wq : p.am_Wq;
        const float* bq = isJob ? p.aj_bq : p.am_bq;
        const int i = threadIdx.x;
        float a = bq[i];
#pragma unroll
        for (int k = 0; k < 16; ++k) a = fmaf(Wq[i * 16 + k], p.last_j[k], a);
        qks[i] = a;
    }
    __syncthreads();
    float qk[16];
#pragma unroll
    for (int i = 0; i < 16; ++i) qk[i] = qks[i];

    v2f e0[16], e1[16];
    emb16_v2(x0, W1, b1, W2, b2, e0);
    emb16_v2(x1, W1, b1, W2, b2, e1);
    if (TIER >= 1)
        ecache_store4((isJob ? p.Ej : p.Em) + (size_t)b0 * EBLK, (int)threadIdx.x, e0, e1);
    if (TIER == 2) {
        // precompute the query-independent matvec for the B (jobs) / D (machines) sweep
        const float* WrX = isJob ? p.ja_Wr : p.ma_Wr;
        v2f w0[16], w1[16];
        wr_mv2(e0, e1, WrX, w0, w1);
        ecache_store4((isJob ? p.Wj : p.Wm) + (size_t)b0 * EBLK, (int)threadIdx.x, w0, w1);
    }
    v2f lg0 = att_logit_v2(e0, qk, Wr, V);
    v2f lg1 = att_logit_v2(e1, qk, Wr, V);
    // |logit| <= sum|V| ~ 0.6 -> exp never overflows; no max-shift needed.
    v2f w01, w23;
    w01.x = v ? __expf(lg0.x) : 0.0f;
    w01.y = v ? __expf(lg0.y) : 0.0f;
    w23.x = v ? __expf(lg1.x) : 0.0f;
    w23.y = v ? __expf(lg1.y) : 0.0f;
    float l = (w01.x + w01.y) + (w23.x + w23.y);
    float s[16];
    wsum4(e0, e1, w01, w23, s);

    block_sum17(l, s, p.S + (isJob ? P1J : P1M) + (size_t)b0 * 17);
}

// ---------------------------------------------------------------------------
// Combine partials -> g (g1 or g2) -> next-stage qk vector. Single block.
// ---------------------------------------------------------------------------
__global__ __launch_bounds__(BLK) void k_combine_g(Params p, int phase) {
    const float* PJ = p.S + P1J;
    const float* PM = p.S + P1M;
    float lJ = 0.0f, lM = 0.0f, sJ[16], sM[16];
#pragma unroll
    for (int c = 0; c < 16; ++c) { sJ[c] = 0.0f; sM[c] = 0.0f; }
    for (int i = threadIdx.x; i < GB_J; i += BLK) {
        lJ += PJ[i * 17];
#pragma unroll
        for (int c = 0; c < 16; ++c) sJ[c] += PJ[i * 17 + 1 + c];
    }
    for (int i = threadIdx.x; i < GB_M; i += BLK) {
        lM += PM[i * 17];
#pragma unroll
        for (int c = 0; c < 16; ++c) sM[c] += PM[i * 17 + 1 + c];
    }
    __shared__ float totJ[17], totM[17];
    block_sum17(lJ, sJ, totJ);
    block_sum17(lM, sM, totM);
    __syncthreads();

    __shared__ float cb[48], gbuf[16];
    if (threadIdx.x < 16) {
        int i = threadIdx.x;
        cb[i]      = phase ? p.S[S_EJS + i] : p.last_j[i];
        cb[16 + i] = totJ[1 + i] / totJ[0];   // softmax-weighted sum / partition
        cb[32 + i] = totM[1 + i] / totM[0];
    }
    __syncthreads();
    const float* gW  = phase ? p.g2W : p.g1W;
    const float* gbv = phase ? p.g2b : p.g1b;
    if (threadIdx.x < 16) {
        int i = threadIdx.x;
        float a = gbv[i];
#pragma unroll
        for (int k = 0; k < 48; ++k) a = fmaf(gW[i * 48 + k], cb[k], a);
        gbuf[i] = fast_tanh(a);
    }
    __syncthreads();
    const float* Wq = phase ? p.ma_Wq : p.ja_Wq;
    const float* bq = phase ? p.ma_bq : p.ja_bq;
    const int off = phase ? S_QKMA : S_QKJA;
    if (threadIdx.x < 16) {
        int i = threadIdx.x;
        float a = bq[i];
#pragma unroll
        for (int k = 0; k < 16; ++k) a = fmaf(Wq[i * 16 + k], gbuf[k], a);
        p.S[off + i] = a;
    }
}

// ---------------------------------------------------------------------------
// K3: job pointer logits -> masked argmax + sum-exp partials. Rows (4t..4t+3).
// TIER==2: load precomputed wr (same bytes as e, no matvec).
// ---------------------------------------------------------------------------
template <int TIER>
__global__ __launch_bounds__(BLK) void k_jlogits(Params p) {
    const int r0 = blockIdx.x * ROWS_PER_BLK + 4 * (int)threadIdx.x;
    const bool v = r0 < NJ;
    const size_t a0 = v ? (size_t)r0 : 0;
    const size_t d  = v ? 1 : 0;

    int4 mq = make_int4(0, 0, 0, 0);
    if (v) mq = *reinterpret_cast<const int4*>(p.mask + r0);   // r0 mult of 4 -> 16B aligned

    float qk[16];
#pragma unroll
    for (int i = 0; i < 16; ++i) qk[i] = p.S[S_QKJA + i];

    v2f lg0, lg1;
    if (TIER == 2) {
        v2f w0[16], w1[16];
        ecache_load4(p.Wj + (size_t)blockIdx.x * EBLK, (int)threadIdx.x, w0, w1);
        lg0 = att_logit_pre(w0, qk, p.ja_V);
        lg1 = att_logit_pre(w1, qk, p.ja_V);
    } else if (TIER == 1) {
        v2f e0[16], e1[16];
        ecache_load4(p.Ej + (size_t)blockIdx.x * EBLK, (int)threadIdx.x, e0, e1);
        lg0 = att_logit_v2(e0, qk, p.ja_Wr, p.ja_V);
        lg1 = att_logit_v2(e1, qk, p.ja_Wr, p.ja_V);
    } else {
        v2f x0[16], x1[16], e0[16], e1[16];
        load16_v2(p.jobs, a0, a0 + d, x0);
        load16_v2(p.jobs, a0 + 2 * d, a0 + 3 * d, x1);
        emb16_v2(x0, p.jW1, p.jb1, p.jW2, p.jb2, e0);
        emb16_v2(x1, p.jW1, p.jb1, p.jW2, p.jb2, e1);
        lg0 = att_logit_v2(e0, qk, p.ja_Wr, p.ja_V);
        lg1 = att_logit_v2(e1, qk, p.ja_Wr, p.ja_V);
    }

    const bool m0 = v && (mq.x != 0);
    const bool m1 = v && (mq.y != 0);
    const bool m2 = v && (mq.z != 0);
    const bool m3 = v && (mq.w != 0);
    float l = (m0 ? __expf(lg0.x) : 0.0f) + (m1 ? __expf(lg0.y) : 0.0f)
            + (m2 ? __expf(lg1.x) : 0.0f) + (m3 ? __expf(lg1.y) : 0.0f);
    float am0 = m0 ? lg0.x : NEGV - 1.0f;  // invalid rows below masked NEG
    float am1 = m1 ? lg0.y : NEGV - 1.0f;
    float am2 = m2 ? lg1.x : NEGV - 1.0f;
    float am3 = m3 ? lg1.y : NEGV - 1.0f;
    float best = am0; int bi = r0;
    if (am1 > best) { best = am1; bi = r0 + 1; }
    if (am2 > best) { best = am2; bi = r0 + 2; }
    if (am3 > best) { best = am3; bi = r0 + 3; }

    l = wave_reduce_sum(l);
    wave_reduce_argmax(best, bi);
    __shared__ float rl[4], rv[4];
    __shared__ int ri[4];
    int w = threadIdx.x >> 6, ln = threadIdx.x & 63;
    if (ln == 0) { rl[w] = l; rv[w] = best; ri[w] = bi; }
    __syncthreads();
    if (threadIdx.x == 0) {
        float L = rl[0] + rl[1] + rl[2] + rl[3];
        float vv = rv[0]; int i = ri[0];
#pragma unroll
        for (int k = 1; k < 4; ++k)
            if (rv[k] > vv || (rv[k] == vv && ri[k] < i)) { vv = rv[k]; i = ri[k]; }
        p.S[P2V + blockIdx.x] = vv;
        p.S[P2I + blockIdx.x] = (float)i;   // exact: i < 2^24
        p.S[P2L + blockIdx.x] = L;
    }
}

// ---------------------------------------------------------------------------
// C2: global argmax over job logits; logp_j; e_js = emb(jobs[sel_j]); qk2j/qk2m
// ---------------------------------------------------------------------------
__global__ __launch_bounds__(BLK) void k_combine2(Params p) {
    float v = -3.4e38f; int vi = 0x7fffffff; float l = 0.0f;
    for (int i = threadIdx.x; i < GB_J; i += BLK) {
        float pv = p.S[P2V + i];
        int pi = (int)p.S[P2I + i];
        if (pv > v || (pv == v && pi < vi)) { v = pv; vi = pi; }
        l += p.S[P2L + i];
    }
    l = block_sum(l);
    block_argmax(v, vi);
    const int sel = vi;

    __shared__ float xb[16], hb[16], eb[16];
    if (threadIdx.x < 16) xb[threadIdx.x] = p.jobs[(size_t)sel * 16 + threadIdx.x];
    __syncthreads();
    if (threadIdx.x < 16) {
        int i = threadIdx.x;
        float a = p.jb1[i];
#pragma unroll
        for (int k = 0; k < 16; ++k) a = fmaf(p.jW1[i * 16 + k], xb[k], a);
        hb[i] = fast_tanh(a);
    }
    __syncthreads();
    if (threadIdx.x < 16) {
        int i = threadIdx.x;
        float a = p.jb2[i];
#pragma unroll
        for (int k = 0; k < 16; ++k) a = fmaf(p.jW2[i * 16 + k], hb[k], a);
        float e = fast_tanh(a);
        eb[i] = e;
        p.S[S_EJS + i] = e;
    }
    __syncthreads();
    if (threadIdx.x < 16) {
        int i = threadIdx.x;
        float a1 = p.aj_bq[i], a2 = p.am_bq[i];
#pragma unroll
        for (int k = 0; k < 16; ++k) {
            a1 = fmaf(p.aj_Wq[i * 16 + k], eb[k], a1);
            a2 = fmaf(p.am_Wq[i * 16 + k], eb[k], a2);
        }
        p.S[S_QK2J + i] = a1;
        p.S[S_QK2M + i] = a2;
    }
    if (threadIdx.x == 0) {
        p.S[S_LOGPJ] = v - logf(l);     // log_softmax at the argmax
        p.S[S_SELJ] = (float)sel;
    }
}

// ---------------------------------------------------------------------------
// K4: glimpse-2 over jobs (aj_*) and machines (am_*), query e_js. Rows (4t..4t+3).
// Reads the e-cache (tier >= 1); writes partials into the P1 buffers.
// ---------------------------------------------------------------------------
template <bool CACHE>
__global__ __launch_bounds__(BLK) void k_glimpse2(Params p) {
    const bool isJob = blockIdx.x < GB_J;
    const float* Wr = isJob ? p.aj_Wr : p.am_Wr;
    const float* V  = isJob ? p.aj_V  : p.am_V;
    const float* E  = isJob ? p.Ej : p.Em;
    const float* X  = isJob ? p.jobs : p.machines;
    const float* W1 = isJob ? p.jW1 : p.mW1;
    const float* b1 = isJob ? p.jb1 : p.mb1;
    const float* W2 = isJob ? p.jW2 : p.mW2;
    const float* b2 = isJob ? p.jb2 : p.mb2;
    const int n  = isJob ? NJ : NM;
    const int b0 = isJob ? (int)blockIdx.x : (int)blockIdx.x - GB_J;
    const int qoff = isJob ? S_QK2J : S_QK2M;

    const int r0 = b0 * ROWS_PER_BLK + 4 * (int)threadIdx.x;
    const bool v = r0 < n;
    const size_t a0 = v ? (size_t)r0 : 0;
    const size_t d  = v ? 1 : 0;

    v2f e0[16], e1[16];
    if (CACHE) {
        ecache_load4(E + (size_t)b0 * EBLK, (int)threadIdx.x, e0, e1);
    } else {
        v2f x0[16], x1[16];
        load16_v2(X, a0, a0 + d, x0);
        load16_v2(X, a0 + 2 * d, a0 + 3 * d, x1);
        emb16_v2(x0, W1, b1, W2, b2, e0);
        emb16_v2(x1, W1, b1, W2, b2, e1);
    }
    float qk[16];
#pragma unroll
    for (int i = 0; i < 16; ++i) qk[i] = p.S[qoff + i];

    v2f lg0 = att_logit_v2(e0, qk, Wr, V);
    v2f lg1 = att_logit_v2(e1, qk, Wr, V);
    v2f w01, w23;
    w01.x = v ? __expf(lg0.x) : 0.0f;
    w01.y = v ? __expf(lg0.y) : 0.0f;
    w23.x = v ? __expf(lg1.x) : 0.0f;
    w23.y = v ? __expf(lg1.y) : 0.0f;
    float l = (w01.x + w01.y) + (w23.x + w23.y);
    float s[16];
    wsum4(e0, e1, w01, w23, s);

    block_sum17(l, s, p.S + (isJob ? P1J : P1M) + (size_t)b0 * 17);
}

// ---------------------------------------------------------------------------
// K5: machine logits -> argmax + sum-exp partials. Rows (4t..4t+3).
// TIER==2: load precomputed wr (same bytes, no matvec). Writes P2 buffers.
// ---------------------------------------------------------------------------
template <int TIER>
__global__ __launch_bounds__(BLK) void k_mlogits(Params p) {
    const int r0 = blockIdx.x * ROWS_PER_BLK + 4 * (int)threadIdx.x;
    const bool v = r0 < NM;
    const size_t a0 = v ? (size_t)r0 : 0;
    const size_t d  = v ? 1 : 0;

    float qk[16];
#pragma unroll
    for (int i = 0; i < 16; ++i) qk[i] = p.S[S_QKMA + i];

    v2f lg0, lg1;
    if (TIER == 2) {
        v2f w0[16], w1[16];
        ecache_load4(p.Wm + (size_t)blockIdx.x * EBLK, (int)threadIdx.x, w0, w1);
        lg0 = att_logit_pre(w0, qk, p.ma_V);
        lg1 = att_logit_pre(w1, qk, p.ma_V);
    } else if (TIER == 1) {
        v2f e0[16], e1[16];
        ecache_load4(p.Em + (size_t)blockIdx.x * EBLK, (int)threadIdx.x, e0, e1);
        lg0 = att_logit_v2(e0, qk, p.ma_Wr, p.ma_V);
        lg1 = att_logit_v2(e1, qk, p.ma_Wr, p.ma_V);
    } else {
        v2f x0[16], x1[16], e0[16], e1[16];
        load16_v2(p.machines, a0, a0 + d, x0);
        load16_v2(p.machines, a0 + 2 * d, a0 + 3 * d, x1);
        emb16_v2(x0, p.mW1, p.mb1, p.mW2, p.mb2, e0);
        emb16_v2(x1, p.mW1, p.mb1, p.mW2, p.mb2, e1);
        lg0 = att_logit_v2(e0, qk, p.ma_Wr, p.ma_V);
        lg1 = att_logit_v2(e1, qk, p.ma_Wr, p.ma_V);
    }

    float l = (v ? __expf(lg0.x) : 0.0f) + (v ? __expf(lg0.y) : 0.0f)
            + (v ? __expf(lg1.x) : 0.0f) + (v ? __expf(lg1.y) : 0.0f);
    float am0 = v ? lg0.x : -3.4e38f;
    float am1 = v ? lg0.y : -3.4e38f;
    float am2 = v ? lg1.x : -3.4e38f;
    float am3 = v ? lg1.y : -3.4e38f;
    float best = am0; int bi = r0;
    if (am1 > best) { best = am1; bi = r0 + 1; }
    if (am2 > best) { best = am2; bi = r0 + 2; }
    if (am3 > best) { best = am3; bi = r0 + 3; }

    l = wave_reduce_sum(l);
    wave_reduce_argmax(best, bi);
    __shared__ float rl[4], rv[4];
    __shared__ int ri[4];
    int w = threadIdx.x >> 6, ln = threadIdx.x & 63;
    if (ln == 0) { rl[w] = l; rv[w] = best; ri[w] = bi; }
    __syncthreads();
    if (threadIdx.x == 0) {
        float L = rl[0] + rl[1] + rl[2] + rl[3];
        float vv = rv[0]; int i = ri[0];
#pragma unroll
        for (int k = 1; k < 4; ++k)
            if (rv[k] > vv || (rv[k] == vv && ri[k] < i)) { vv = rv[k]; i = ri[k]; }
        p.S[P2V + blockIdx.x] = vv;
        p.S[P2I + blockIdx.x] = (float)i;
        p.S[P2L + blockIdx.x] = L;
    }
}

// ---------------------------------------------------------------------------
// C4: final combine -> outputs [sel_j, sel_m, logpas] as float32
// ---------------------------------------------------------------------------
__global__ __launch_bounds__(BLK) void k_combine4(Params p) {
    float v = -3.4e38f; int vi = 0x7fffffff; float l = 0.0f;
    for (int i = threadIdx.x; i < GB_M; i += BLK) {
        float pv = p.S[P2V + i];
        int pi = (int)p.S[P2I + i];
        if (pv > v || (pv == v && pi < vi)) { v = pv; vi = pi; }
        l += p.S[P2L + i];
    }
    l = block_sum(l);
    block_argmax(v, vi);
    if (threadIdx.x == 0) {
        p.out[0] = p.S[S_SELJ];
        p.out[1] = (float)vi;
        p.out[2] = p.S[S_LOGPJ] + (v - logf(l));
    }
}

// ---------------------------------------------------------------------------
extern "C" void kernel_launch(void* const* d_in, const int* in_sizes, int n_in,
                              void* d_out, int out_size, void* d_ws, size_t ws_size,
                              hipStream_t stream) {
    Params p;
    p.jobs     = (const float*)d_in[0];
    p.machines = (const float*)d_in[1];
    p.mask     = (const int*)d_in[2];
    p.jW1 = (const float*)d_in[3];  p.jb1 = (const float*)d_in[4];
    p.jW2 = (const float*)d_in[5];  p.jb2 = (const float*)d_in[6];
    p.mW1 = (const float*)d_in[7];  p.mb1 = (const float*)d_in[8];
    p.mW2 = (const float*)d_in[9];  p.mb2 = (const float*)d_in[10];
    p.aj_Wq = (const float*)d_in[11]; p.aj_bq = (const float*)d_in[12];
    p.aj_Wr = (const float*)d_in[13]; p.aj_V  = (const float*)d_in[14];
    p.am_Wq = (const float*)d_in[15]; p.am_bq = (const float*)d_in[16];
    p.am_Wr = (const float*)d_in[17]; p.am_V  = (const float*)d_in[18];
    p.ja_Wq = (const float*)d_in[19]; p.ja_bq = (const float*)d_in[20];
    p.ja_Wr = (const float*)d_in[21]; p.ja_V  = (const float*)d_in[22];
    p.ma_Wq = (const float*)d_in[23]; p.ma_bq = (const float*)d_in[24];
    p.ma_Wr = (const float*)d_in[25]; p.ma_V  = (const float*)d_in[26];
    p.g1W = (const float*)d_in[27]; p.g1b = (const float*)d_in[28];
    p.g2W = (const float*)d_in[29]; p.g2b = (const float*)d_in[30];
    p.last_j = (const float*)d_in[31];
    p.S = (float*)d_ws;
    p.Ej = (float*)d_ws + E_OFF;
    p.Em = p.Ej + (size_t)GB_J * EBLK;
    p.Wj = p.Ej + (size_t)GB_TOT * EBLK;
    p.Wm = p.Wj + (size_t)GB_J * EBLK;
    p.out = (float*)d_out;

    const size_t need_e    = (E_OFF + (size_t)GB_TOT * EBLK) * sizeof(float);
    const size_t need_full = (E_OFF + 2 * (size_t)GB_TOT * EBLK) * sizeof(float);
    const int tier = (ws_size >= need_full) ? 2 : (ws_size >= need_e ? 1 : 0);

    if (tier == 2) {
        k_emb_g1<2><<<GB_TOT, BLK, 0, stream>>>(p);
        k_combine_g<<<1, BLK, 0, stream>>>(p, 0);
        k_jlogits<2><<<GB_J, BLK, 0, stream>>>(p);
        k_combine2<<<1, BLK, 0, stream>>>(p);
        k_glimpse2<true><<<GB_TOT, BLK, 0, stream>>>(p);
        k_combine_g<<<1, BLK, 0, stream>>>(p, 1);
        k_mlogits<2><<<GB_M, BLK, 0, stream>>>(p);
        k_combine4<<<1, BLK, 0, stream>>>(p);
    } else if (tier == 1) {
        k_emb_g1<1><<<GB_TOT, BLK, 0, stream>>>(p);
        k_combine_g<<<1, BLK, 0, stream>>>(p, 0);
        k_jlogits<1><<<GB_J, BLK, 0, stream>>>(p);
        k_combine2<<<1, BLK, 0, stream>>>(p);
        k_glimpse2<true><<<GB_TOT, BLK, 0, stream>>>(p);
        k_combine_g<<<1, BLK, 0, stream>>>(p, 1);
        k_mlogits<1><<<GB_M, BLK, 0, stream>>>(p);
        k_combine4<<<1, BLK, 0, stream>>>(p);
    } else {
        k_emb_g1<0><<<GB_TOT, BLK, 0, stream>>>(p);
        k_combine_g<<<1, BLK, 0, stream>>>(p, 0);
        k_jlogits<0><<<GB_J, BLK, 0, stream>>>(p);
        k_combine2<<<1, BLK, 0, stream>>>(p);
        k_glimpse2<false><<<GB_TOT, BLK, 0, stream>>>(p);
        k_combine_g<<<1, BLK, 0, stream>>>(p, 1);
        k_mlogits<0><<<GB_M, BLK, 0, stream>>>(p);
        k_combine4<<<1, BLK, 0, stream>>>(p);
    }
}

// Round 13
// 314.369 us; speedup vs baseline: 1.0450x; 1.0450x over previous
//
#include <hip/hip_runtime.h>
#include <cstddef>
#include <cstdint>

// ---------------------------------------------------------------------------
// attention_net_noc: pointer-network decode step.
// R16 = R15's query-independent matvec precompute, register-frugal.
// R15 evidence: B+D with precomputed wr saved ~58us (B 68->~25), numerics
// pass (absmax 0) -- but producer A hit VGPR 184 / occupancy 11% because
// wr_mv2 materialized w0[16],w1[16] before storing (+104us). Fix:
//  (1) wr_store computes TWO output rows at a time and stores the float4
//      immediately -> peak extra liveness ~8 VGPR.
//  (2) split production: A's jobs-blocks write Wj=ja_Wr@e (+64MB on 2/3 of
//      blocks); C's machines-blocks write Wm=ma_Wr@e (+32MB on 1/3 of C,
//      e already in registers). B and D read wr (same bytes as e, ~1/3 VALU).
// Tiers: 2=full (e+wr, ~192MB), 1=e-only (=R14 best, 282.5us), 0=none.
// ---------------------------------------------------------------------------

constexpr int NJ = 1000000;
constexpr int NM = 500000;
constexpr float NEGV = -1e8f;

constexpr int BLK = 256;
constexpr int ROWS_PER_BLK = 1024;           // 4 adjacent rows per thread
constexpr int GB_J = (NJ + ROWS_PER_BLK - 1) / ROWS_PER_BLK;   // 977
constexpr int GB_M = (NM + ROWS_PER_BLK - 1) / ROWS_PER_BLK;   // 489
constexpr int GB_TOT = GB_J + GB_M;                             // 1466
constexpr int EBLK = ROWS_PER_BLK * 16;                         // 16384 floats/tile

// ---- workspace layout (float offsets from start of d_ws) ----
constexpr int S_QKJA = 0;    // 16: ja_Wq@g1 + ja_bq
constexpr int S_QK2J = 16;   // 16: aj_Wq@e_js + aj_bq
constexpr int S_QK2M = 32;   // 16: am_Wq@e_js + am_bq
constexpr int S_EJS  = 48;   // 16: E_j[sel_j]
constexpr int S_QKMA = 64;   // 16: ma_Wq@g2 + ma_bq
constexpr int S_LOGPJ = 80;
constexpr int S_SELJ  = 81;  // stored as float (exact, < 2^24)
constexpr int P1J = 128;                       // GB_J*17 glimpse partials (l, s[16])
constexpr int P1M = P1J + GB_J * 17;
constexpr int P2V = P1M + GB_M * 17;           // GB_J argmax vals (mlogits reuses)
constexpr int P2I = P2V + GB_J;
constexpr int P2L = P2I + GB_J;
constexpr size_t E_OFF = 65536;                // float offset of E cache tiles
static_assert(P2L + GB_J <= (int)E_OFF, "partials overflow into E cache");
static_assert(NJ % 4 == 0 && NM % 4 == 0, "4-row packing needs n % 4 == 0");

typedef float v2f __attribute__((ext_vector_type(2)));

struct Params {
    const float *jobs, *machines;
    const int *mask;
    const float *jW1, *jb1, *jW2, *jb2;
    const float *mW1, *mb1, *mW2, *mb2;
    const float *aj_Wq, *aj_bq, *aj_Wr, *aj_V;
    const float *am_Wq, *am_bq, *am_Wr, *am_V;
    const float *ja_Wq, *ja_bq, *ja_Wr, *ja_V;
    const float *ma_Wq, *ma_bq, *ma_Wr, *ma_V;
    const float *g1W, *g1b, *g2W, *g2b, *last_j;
    float *S;        // smalls + partials (in ws)
    float *Ej, *Em;  // embedding cache tiles (tier >= 1)
    float *Wj, *Wm;  // ja_Wr@e (jobs) / ma_Wr@e (machines) caches (tier 2)
    float *out;
};

// ---------------------------------------------------------------------------
// device helpers (verified R9-R14 versions)
// ---------------------------------------------------------------------------

__device__ __forceinline__ float fast_tanh(float x) {
    float e = __builtin_amdgcn_exp2f(x * 2.8853900817779268f);  // 2/ln2
    float r = __builtin_amdgcn_rcpf(e + 1.0f);
    return fmaf(-2.0f, r, 1.0f);
}

__device__ __forceinline__ v2f vbc(float a) { v2f r; r.x = a; r.y = a; return r; }

__device__ __forceinline__ v2f vfma(float w, v2f b, v2f c) {
    return __builtin_elementwise_fma(vbc(w), b, c);
}
__device__ __forceinline__ v2f vfma2(v2f a, v2f b, v2f c) {
    return __builtin_elementwise_fma(a, b, c);
}
__device__ __forceinline__ v2f vtanh(v2f a) {
    v2f r; r.x = fast_tanh(a.x); r.y = fast_tanh(a.y); return r;
}

__device__ __forceinline__ void load16(const float* __restrict__ X, size_t r, float (&x)[16]) {
    const float4* p4 = reinterpret_cast<const float4*>(X) + r * 4;
    float4 a = p4[0], b = p4[1], c = p4[2], d = p4[3];
    x[0]=a.x; x[1]=a.y; x[2]=a.z; x[3]=a.w;
    x[4]=b.x; x[5]=b.y; x[6]=b.z; x[7]=b.w;
    x[8]=c.x; x[9]=c.y; x[10]=c.z; x[11]=c.w;
    x[12]=d.x; x[13]=d.y; x[14]=d.z; x[15]=d.w;
}

__device__ __forceinline__ void load16_v2(const float* __restrict__ X, size_t rA, size_t rB,
                                          v2f (&x)[16]) {
    float a[16], b[16];
    load16(X, rA, a);
    load16(X, rB, b);
#pragma unroll
    for (int k = 0; k < 16; ++k) { x[k].x = a[k]; x[k].y = b[k]; }
}

// tile for 4 rows/thread: [8 kp][2 pairs][256 threads * float4]
__device__ __forceinline__ void ecache_store4(float* __restrict__ Eb, int t,
                                              const v2f (&e0)[16], const v2f (&e1)[16]) {
    float4* p4 = reinterpret_cast<float4*>(Eb);
#pragma unroll
    for (int kp = 0; kp < 8; ++kp) {
        p4[kp * 512 + t]       = make_float4(e0[2*kp].x, e0[2*kp].y, e0[2*kp+1].x, e0[2*kp+1].y);
        p4[kp * 512 + 256 + t] = make_float4(e1[2*kp].x, e1[2*kp].y, e1[2*kp+1].x, e1[2*kp+1].y);
    }
}
__device__ __forceinline__ void ecache_load4(const float* __restrict__ Eb, int t,
                                             v2f (&e0)[16], v2f (&e1)[16]) {
    const float4* p4 = reinterpret_cast<const float4*>(Eb);
#pragma unroll
    for (int kp = 0; kp < 8; ++kp) {
        float4 q0 = p4[kp * 512 + t];
        float4 q1 = p4[kp * 512 + 256 + t];
        e0[2*kp].x = q0.x;   e0[2*kp].y = q0.y;
        e0[2*kp+1].x = q0.z; e0[2*kp+1].y = q0.w;
        e1[2*kp].x = q1.x;   e1[2*kp].y = q1.y;
        e1[2*kp+1].x = q1.z; e1[2*kp+1].y = q1.w;
    }
}

// Register-frugal wr = Wr@e producer: computes TWO output rows (2kp, 2kp+1)
// for both pairs, packs and stores immediately. Peak extra liveness ~4 v2f.
__device__ __forceinline__ void wr_store(const v2f (&e0)[16], const v2f (&e1)[16],
                                         const float* __restrict__ Wr,
                                         float* __restrict__ Wb, int t) {
    float4* p4 = reinterpret_cast<float4*>(Wb);
#pragma unroll
    for (int kp = 0; kp < 8; ++kp) {
        v2f a0 = vbc(0.0f), a1 = vbc(0.0f), b0 = vbc(0.0f), b1 = vbc(0.0f);
#pragma unroll
        for (int k = 0; k < 16; ++k) {
            const float wA = Wr[(2 * kp) * 16 + k];
            const float wB = Wr[(2 * kp + 1) * 16 + k];
            a0 = vfma(wA, e0[k], a0);
            a1 = vfma(wB, e0[k], a1);
            b0 = vfma(wA, e1[k], b0);
            b1 = vfma(wB, e1[k], b1);
        }
        p4[kp * 512 + t]       = make_float4(a0.x, a0.y, a1.x, a1.y);
        p4[kp * 512 + 256 + t] = make_float4(b0.x, b0.y, b1.x, b1.y);
    }
}

__device__ __forceinline__ void emb16_v2(const v2f (&x)[16],
                                         const float* __restrict__ W1, const float* __restrict__ b1,
                                         const float* __restrict__ W2, const float* __restrict__ b2,
                                         v2f (&e)[16]) {
    v2f h[16];
#pragma unroll
    for (int i = 0; i < 16; ++i) {
        v2f a = vbc(b1[i]);
#pragma unroll
        for (int k = 0; k < 16; ++k) a = vfma(W1[i * 16 + k], x[k], a);
        h[i] = vtanh(a);
    }
#pragma unroll
    for (int i = 0; i < 16; ++i) {
        v2f a = vbc(b2[i]);
#pragma unroll
        for (int k = 0; k < 16; ++k) a = vfma(W2[i * 16 + k], h[k], a);
        e[i] = vtanh(a);
    }
}

// full logit: tanh(qk + Wr @ e) . V
__device__ __forceinline__ v2f att_logit_v2(const v2f (&e)[16], const float (&qk)[16],
                                            const float* __restrict__ Wr,
                                            const float* __restrict__ V) {
    v2f acc = vbc(0.0f);
#pragma unroll
    for (int i = 0; i < 16; ++i) {
        v2f r = vbc(qk[i]);
#pragma unroll
        for (int k = 0; k < 16; ++k) r = vfma(Wr[i * 16 + k], e[k], r);
        acc = vfma2(vbc(V[i]), vtanh(r), acc);
    }
    return acc;
}

// precomputed-wr logit: tanh(qk + wr) . V  (~1/3 the slots)
__device__ __forceinline__ v2f att_logit_pre(const v2f (&wr)[16], const float (&qk)[16],
                                             const float* __restrict__ V) {
    v2f acc = vbc(0.0f);
#pragma unroll
    for (int i = 0; i < 16; ++i)
        acc = vfma2(vbc(V[i]), vtanh(vbc(qk[i]) + wr[i]), acc);
    return acc;
}

__device__ __forceinline__ float wave_reduce_sum(float v) {
#pragma unroll
    for (int off = 32; off > 0; off >>= 1) v += __shfl_xor(v, off, 64);
    return v;
}

__device__ __forceinline__ void wave_reduce_argmax(float &v, int &idx) {
#pragma unroll
    for (int off = 32; off > 0; off >>= 1) {
        float ov = __shfl_xor(v, off, 64);
        int oi = __shfl_xor(idx, off, 64);
        if (ov > v || (ov == v && oi < idx)) { v = ov; idx = oi; }
    }
}

__device__ __forceinline__ float block_sum(float v) {
    __shared__ float sm[4];
    v = wave_reduce_sum(v);
    __syncthreads();
    if ((threadIdx.x & 63) == 0) sm[threadIdx.x >> 6] = v;
    __syncthreads();
    return sm[0] + sm[1] + sm[2] + sm[3];
}

__device__ __forceinline__ void block_argmax(float &v, int &i) {
    __shared__ float sv[4];
    __shared__ int si[4];
    wave_reduce_argmax(v, i);
    __syncthreads();
    if ((threadIdx.x & 63) == 0) { sv[threadIdx.x >> 6] = v; si[threadIdx.x >> 6] = i; }
    __syncthreads();
    float bv = sv[0]; int bi = si[0];
#pragma unroll
    for (int k = 1; k < 4; ++k)
        if (sv[k] > bv || (sv[k] == bv && si[k] < bi)) { bv = sv[k]; bi = si[k]; }
    v = bv; i = bi;
}

// Block-reduce (l, s[16]) -> dst[17]. dst[0]=l, dst[1+j]=s[j]. Verified R7-R15.
__device__ __forceinline__ void block_sum17(float l, const float (&s)[16], float* dst) {
    const int lane = threadIdx.x & 63;
    float c[8];
#pragma unroll
    for (int j = 0; j < 8; ++j) {          // xor 1: 16 -> 8
        const bool hi = lane & 1;
        float t = __shfl_xor(hi ? s[j] : s[j + 8], 1, 64);
        c[j] = (hi ? s[j + 8] : s[j]) + t;
    }
    float d[4];
#pragma unroll
    for (int j = 0; j < 4; ++j) {          // xor 2: 8 -> 4
        const bool hi = lane & 2;
        float t = __shfl_xor(hi ? c[j] : c[j + 4], 2, 64);
        d[j] = (hi ? c[j + 4] : c[j]) + t;
    }
    float e2[2];
#pragma unroll
    for (int j = 0; j < 2; ++j) {          // xor 4: 4 -> 2
        const bool hi = lane & 4;
        float t = __shfl_xor(hi ? d[j] : d[j + 2], 4, 64);
        e2[j] = (hi ? d[j + 2] : d[j]) + t;
    }
    float f;
    {                                       // xor 8: 2 -> 1
        const bool hi = lane & 8;
        float t = __shfl_xor(hi ? e2[0] : e2[1], 8, 64);
        f = (hi ? e2[1] : e2[0]) + t;
    }
    f += __shfl_xor(f, 16, 64);
    f += __shfl_xor(f, 32, 64);
#pragma unroll
    for (int off = 32; off > 0; off >>= 1) l += __shfl_xor(l, off, 64);

    const int idx = ((lane & 1) << 3) | ((lane & 2) << 1) | ((lane & 4) >> 1) | ((lane & 8) >> 3);
    __shared__ float red[4][17];
    const int w = threadIdx.x >> 6;
    __syncthreads();                        // guard reuse across successive calls
    if (lane < 16) red[w][1 + idx] = f;
    if (lane == 0) red[w][0] = l;
    __syncthreads();
    if (threadIdx.x < 17)
        dst[threadIdx.x] = red[0][threadIdx.x] + red[1][threadIdx.x] + red[2][threadIdx.x] + red[3][threadIdx.x];
}

// weighted sum of 4 rows: s[i] = w01 . e0[i] + w23 . e1[i]
__device__ __forceinline__ void wsum4(const v2f (&e0)[16], const v2f (&e1)[16],
                                      v2f w01, v2f w23, float (&s)[16]) {
#pragma unroll
    for (int i = 0; i < 16; ++i) {
        v2f t = vfma2(w23, e1[i], w01 * e0[i]);
        s[i] = t.x + t.y;
    }
}

// ---------------------------------------------------------------------------
// K1: embeddings (TIER>=1: cache e; TIER==2 jobs-blocks: also cache ja_Wr@e)
// + glimpse-1 partials. Rows (4t..4t+3). blocks [0,GB_J)=jobs, rest machines.
// ---------------------------------------------------------------------------
template <int TIER>
__global__ __launch_bounds__(BLK) void k_emb_g1(Params p) {
    const bool isJob = blockIdx.x < GB_J;
    const float* X  = isJob ? p.jobs : p.machines;
    const float* W1 = isJob ? p.jW1 : p.mW1;
    const float* b1 = isJob ? p.jb1 : p.mb1;
    const float* W2 = isJob ? p.jW2 : p.mW2;
    const float* b2 = isJob ? p.jb2 : p.mb2;
    const float* Wr = isJob ? p.aj_Wr : p.am_Wr;
    const float* V  = isJob ? p.aj_V  : p.am_V;
    const int n  = isJob ? NJ : NM;
    const int b0 = isJob ? (int)blockIdx.x : (int)blockIdx.x - GB_J;

    const int r0 = b0 * ROWS_PER_BLK + 4 * (int)threadIdx.x;
    const bool v = r0 < n;
    const size_t a0 = v ? (size_t)r0 : 0;
    const size_t d  = v ? 1 : 0;

    // issue all 16 global loads first (latency overlaps the qk prologue)
    v2f x0[16], x1[16];
    load16_v2(X, a0, a0 + d, x0);
    load16_v2(X, a0 + 2 * d, a0 + 3 * d, x1);

    __shared__ float qks[16];
    if (threadIdx.x < 16) {
        const float* Wq = isJob ? p.aj_Wq : p.am_Wq;
        const float* bq = isJob ? p.aj_bq : p.am_bq;
        const int i = threadIdx.x;
        float a = bq[i];
#pragma unroll
        for (int k = 0; k < 16; ++k) a = fmaf(Wq[i * 16 + k], p.last_j[k], a);
        qks[i] = a;
    }
    __syncthreads();
    float qk[16];
#pragma unroll
    for (int i = 0; i < 16; ++i) qk[i] = qks[i];

    v2f e0[16], e1[16];
    emb16_v2(x0, W1, b1, W2, b2, e0);
    emb16_v2(x1, W1, b1, W2, b2, e1);
    if (TIER >= 1)
        ecache_store4((isJob ? p.Ej : p.Em) + (size_t)b0 * EBLK, (int)threadIdx.x, e0, e1);
    if (TIER == 2 && isJob)
        wr_store(e0, e1, p.ja_Wr, p.Wj + (size_t)b0 * EBLK, (int)threadIdx.x);

    v2f lg0 = att_logit_v2(e0, qk, Wr, V);
    v2f lg1 = att_logit_v2(e1, qk, Wr, V);
    // |logit| <= sum|V| ~ 0.6 -> exp never overflows; no max-shift needed.
    v2f w01, w23;
    w01.x = v ? __expf(lg0.x) : 0.0f;
    w01.y = v ? __expf(lg0.y) : 0.0f;
    w23.x = v ? __expf(lg1.x) : 0.0f;
    w23.y = v ? __expf(lg1.y) : 0.0f;
    float l = (w01.x + w01.y) + (w23.x + w23.y);
    float s[16];
    wsum4(e0, e1, w01, w23, s);

    block_sum17(l, s, p.S + (isJob ? P1J : P1M) + (size_t)b0 * 17);
}

// ---------------------------------------------------------------------------
// Combine partials -> g (g1 or g2) -> next-stage qk vector. Single block.
// ---------------------------------------------------------------------------
__global__ __launch_bounds__(BLK) void k_combine_g(Params p, int phase) {
    const float* PJ = p.S + P1J;
    const float* PM = p.S + P1M;
    float lJ = 0.0f, lM = 0.0f, sJ[16], sM[16];
#pragma unroll
    for (int c = 0; c < 16; ++c) { sJ[c] = 0.0f; sM[c] = 0.0f; }
    for (int i = threadIdx.x; i < GB_J; i += BLK) {
        lJ += PJ[i * 17];
#pragma unroll
        for (int c = 0; c < 16; ++c) sJ[c] += PJ[i * 17 + 1 + c];
    }
    for (int i = threadIdx.x; i < GB_M; i += BLK) {
        lM += PM[i * 17];
#pragma unroll
        for (int c = 0; c < 16; ++c) sM[c] += PM[i * 17 + 1 + c];
    }
    __shared__ float totJ[17], totM[17];
    block_sum17(lJ, sJ, totJ);
    block_sum17(lM, sM, totM);
    __syncthreads();

    __shared__ float cb[48], gbuf[16];
    if (threadIdx.x < 16) {
        int i = threadIdx.x;
        cb[i]      = phase ? p.S[S_EJS + i] : p.last_j[i];
        cb[16 + i] = totJ[1 + i] / totJ[0];   // softmax-weighted sum / partition
        cb[32 + i] = totM[1 + i] / totM[0];
    }
    __syncthreads();
    const float* gW  = phase ? p.g2W : p.g1W;
    const float* gbv = phase ? p.g2b : p.g1b;
    if (threadIdx.x < 16) {
        int i = threadIdx.x;
        float a = gbv[i];
#pragma unroll
        for (int k = 0; k < 48; ++k) a = fmaf(gW[i * 48 + k], cb[k], a);
        gbuf[i] = fast_tanh(a);
    }
    __syncthreads();
    const float* Wq = phase ? p.ma_Wq : p.ja_Wq;
    const float* bq = phase ? p.ma_bq : p.ja_bq;
    const int off = phase ? S_QKMA : S_QKJA;
    if (threadIdx.x < 16) {
        int i = threadIdx.x;
        float a = bq[i];
#pragma unroll
        for (int k = 0; k < 16; ++k) a = fmaf(Wq[i * 16 + k], gbuf[k], a);
        p.S[off + i] = a;
    }
}

// ---------------------------------------------------------------------------
// K3: job pointer logits -> masked argmax + sum-exp partials. Rows (4t..4t+3).
// TIER==2: read precomputed Wj (same bytes as e, no matvec).
// ---------------------------------------------------------------------------
template <int TIER>
__global__ __launch_bounds__(BLK) void k_jlogits(Params p) {
    const int r0 = blockIdx.x * ROWS_PER_BLK + 4 * (int)threadIdx.x;
    const bool v = r0 < NJ;
    const size_t a0 = v ? (size_t)r0 : 0;
    const size_t d  = v ? 1 : 0;

    int4 mq = make_int4(0, 0, 0, 0);
    if (v) mq = *reinterpret_cast<const int4*>(p.mask + r0);   // r0 mult of 4 -> 16B aligned

    float qk[16];
#pragma unroll
    for (int i = 0; i < 16; ++i) qk[i] = p.S[S_QKJA + i];

    v2f lg0, lg1;
    if (TIER == 2) {
        v2f w0[16], w1[16];
        ecache_load4(p.Wj + (size_t)blockIdx.x * EBLK, (int)threadIdx.x, w0, w1);
        lg0 = att_logit_pre(w0, qk, p.ja_V);
        lg1 = att_logit_pre(w1, qk, p.ja_V);
    } else if (TIER == 1) {
        v2f e0[16], e1[16];
        ecache_load4(p.Ej + (size_t)blockIdx.x * EBLK, (int)threadIdx.x, e0, e1);
        lg0 = att_logit_v2(e0, qk, p.ja_Wr, p.ja_V);
        lg1 = att_logit_v2(e1, qk, p.ja_Wr, p.ja_V);
    } else {
        v2f x0[16], x1[16], e0[16], e1[16];
        load16_v2(p.jobs, a0, a0 + d, x0);
        load16_v2(p.jobs, a0 + 2 * d, a0 + 3 * d, x1);
        emb16_v2(x0, p.jW1, p.jb1, p.jW2, p.jb2, e0);
        emb16_v2(x1, p.jW1, p.jb1, p.jW2, p.jb2, e1);
        lg0 = att_logit_v2(e0, qk, p.ja_Wr, p.ja_V);
        lg1 = att_logit_v2(e1, qk, p.ja_Wr, p.ja_V);
    }

    const bool m0 = v && (mq.x != 0);
    const bool m1 = v && (mq.y != 0);
    const bool m2 = v && (mq.z != 0);
    const bool m3 = v && (mq.w != 0);
    float l = (m0 ? __expf(lg0.x) : 0.0f) + (m1 ? __expf(lg0.y) : 0.0f)
            + (m2 ? __expf(lg1.x) : 0.0f) + (m3 ? __expf(lg1.y) : 0.0f);
    float am0 = m0 ? lg0.x : NEGV - 1.0f;  // invalid rows below masked NEG
    float am1 = m1 ? lg0.y : NEGV - 1.0f;
    float am2 = m2 ? lg1.x : NEGV - 1.0f;
    float am3 = m3 ? lg1.y : NEGV - 1.0f;
    float best = am0; int bi = r0;
    if (am1 > best) { best = am1; bi = r0 + 1; }
    if (am2 > best) { best = am2; bi = r0 + 2; }
    if (am3 > best) { best = am3; bi = r0 + 3; }

    l = wave_reduce_sum(l);
    wave_reduce_argmax(best, bi);
    __shared__ float rl[4], rv[4];
    __shared__ int ri[4];
    int w = threadIdx.x >> 6, ln = threadIdx.x & 63;
    if (ln == 0) { rl[w] = l; rv[w] = best; ri[w] = bi; }
    __syncthreads();
    if (threadIdx.x == 0) {
        float L = rl[0] + rl[1] + rl[2] + rl[3];
        float vv = rv[0]; int i = ri[0];
#pragma unroll
        for (int k = 1; k < 4; ++k)
            if (rv[k] > vv || (rv[k] == vv && ri[k] < i)) { vv = rv[k]; i = ri[k]; }
        p.S[P2V + blockIdx.x] = vv;
        p.S[P2I + blockIdx.x] = (float)i;   // exact: i < 2^24
        p.S[P2L + blockIdx.x] = L;
    }
}

// ---------------------------------------------------------------------------
// C2: global argmax over job logits; logp_j; e_js = emb(jobs[sel_j]); qk2j/qk2m
// ---------------------------------------------------------------------------
__global__ __launch_bounds__(BLK) void k_combine2(Params p) {
    float v = -3.4e38f; int vi = 0x7fffffff; float l = 0.0f;
    for (int i = threadIdx.x; i < GB_J; i += BLK) {
        float pv = p.S[P2V + i];
        int pi = (int)p.S[P2I + i];
        if (pv > v || (pv == v && pi < vi)) { v = pv; vi = pi; }
        l += p.S[P2L + i];
    }
    l = block_sum(l);
    block_argmax(v, vi);
    const int sel = vi;

    __shared__ float xb[16], hb[16], eb[16];
    if (threadIdx.x < 16) xb[threadIdx.x] = p.jobs[(size_t)sel * 16 + threadIdx.x];
    __syncthreads();
    if (threadIdx.x < 16) {
        int i = threadIdx.x;
        float a = p.jb1[i];
#pragma unroll
        for (int k = 0; k < 16; ++k) a = fmaf(p.jW1[i * 16 + k], xb[k], a);
        hb[i] = fast_tanh(a);
    }
    __syncthreads();
    if (threadIdx.x < 16) {
        int i = threadIdx.x;
        float a = p.jb2[i];
#pragma unroll
        for (int k = 0; k < 16; ++k) a = fmaf(p.jW2[i * 16 + k], hb[k], a);
        float e = fast_tanh(a);
        eb[i] = e;
        p.S[S_EJS + i] = e;
    }
    __syncthreads();
    if (threadIdx.x < 16) {
        int i = threadIdx.x;
        float a1 = p.aj_bq[i], a2 = p.am_bq[i];
#pragma unroll
        for (int k = 0; k < 16; ++k) {
            a1 = fmaf(p.aj_Wq[i * 16 + k], eb[k], a1);
            a2 = fmaf(p.am_Wq[i * 16 + k], eb[k], a2);
        }
        p.S[S_QK2J + i] = a1;
        p.S[S_QK2M + i] = a2;
    }
    if (threadIdx.x == 0) {
        p.S[S_LOGPJ] = v - logf(l);     // log_softmax at the argmax
        p.S[S_SELJ] = (float)sel;
    }
}

// ---------------------------------------------------------------------------
// K4: glimpse-2 over jobs (aj_*) and machines (am_*), query e_js. Rows (4t..4t+3).
// TIER==2 machines-blocks: also produce Wm = ma_Wr@e for sweep D.
// Writes partials into the (already consumed) P1 buffers.
// ---------------------------------------------------------------------------
template <int TIER>
__global__ __launch_bounds__(BLK) void k_glimpse2(Params p) {
    const bool isJob = blockIdx.x < GB_J;
    const float* Wr = isJob ? p.aj_Wr : p.am_Wr;
    const float* V  = isJob ? p.aj_V  : p.am_V;
    const float* E  = isJob ? p.Ej : p.Em;
    const float* X  = isJob ? p.jobs : p.machines;
    const float* W1 = isJob ? p.jW1 : p.mW1;
    const float* b1 = isJob ? p.jb1 : p.mb1;
    const float* W2 = isJob ? p.jW2 : p.mW2;
    const float* b2 = isJob ? p.jb2 : p.mb2;
    const int n  = isJob ? NJ : NM;
    const int b0 = isJob ? (int)blockIdx.x : (int)blockIdx.x - GB_J;
    const int qoff = isJob ? S_QK2J : S_QK2M;

    const int r0 = b0 * ROWS_PER_BLK + 4 * (int)threadIdx.x;
    const bool v = r0 < n;
    const size_t a0 = v ? (size_t)r0 : 0;
    const size_t d  = v ? 1 : 0;

    v2f e0[16], e1[16];
    if (TIER >= 1) {
        ecache_load4(E + (size_t)b0 * EBLK, (int)threadIdx.x, e0, e1);
    } else {
        v2f x0[16], x1[16];
        load16_v2(X, a0, a0 + d, x0);
        load16_v2(X, a0 + 2 * d, a0 + 3 * d, x1);
        emb16_v2(x0, W1, b1, W2, b2, e0);
        emb16_v2(x1, W1, b1, W2, b2, e1);
    }
    if (TIER == 2 && !isJob)
        wr_store(e0, e1, p.ma_Wr, p.Wm + (size_t)b0 * EBLK, (int)threadIdx.x);

    float qk[16];
#pragma unroll
    for (int i = 0; i < 16; ++i) qk[i] = p.S[qoff + i];

    v2f lg0 = att_logit_v2(e0, qk, Wr, V);
    v2f lg1 = att_logit_v2(e1, qk, Wr, V);
    v2f w01, w23;
    w01.x = v ? __expf(lg0.x) : 0.0f;
    w01.y = v ? __expf(lg0.y) : 0.0f;
    w23.x = v ? __expf(lg1.x) : 0.0f;
    w23.y = v ? __expf(lg1.y) : 0.0f;
    float l = (w01.x + w01.y) + (w23.x + w23.y);
    float s[16];
    wsum4(e0, e1, w01, w23, s);

    block_sum17(l, s, p.S + (isJob ? P1J : P1M) + (size_t)b0 * 17);
}

// ---------------------------------------------------------------------------
// K5: machine logits -> argmax + sum-exp partials. Rows (4t..4t+3).
// TIER==2: read precomputed Wm (same bytes, no matvec). Writes P2 buffers.
// ---------------------------------------------------------------------------
template <int TIER>
__global__ __launch_bounds__(BLK) void k_mlogits(Params p) {
    const int r0 = blockIdx.x * ROWS_PER_BLK + 4 * (int)threadIdx.x;
    const bool v = r0 < NM;
    const size_t a0 = v ? (size_t)r0 : 0;
    const size_t d  = v ? 1 : 0;

    float qk[16];
#pragma unroll
    for (int i = 0; i < 16; ++i) qk[i] = p.S[S_QKMA + i];

    v2f lg0, lg1;
    if (TIER == 2) {
        v2f w0[16], w1[16];
        ecache_load4(p.Wm + (size_t)blockIdx.x * EBLK, (int)threadIdx.x, w0, w1);
        lg0 = att_logit_pre(w0, qk, p.ma_V);
        lg1 = att_logit_pre(w1, qk, p.ma_V);
    } else if (TIER == 1) {
        v2f e0[16], e1[16];
        ecache_load4(p.Em + (size_t)blockIdx.x * EBLK, (int)threadIdx.x, e0, e1);
        lg0 = att_logit_v2(e0, qk, p.ma_Wr, p.ma_V);
        lg1 = att_logit_v2(e1, qk, p.ma_Wr, p.ma_V);
    } else {
        v2f x0[16], x1[16], e0[16], e1[16];
        load16_v2(p.machines, a0, a0 + d, x0);
        load16_v2(p.machines, a0 + 2 * d, a0 + 3 * d, x1);
        emb16_v2(x0, p.mW1, p.mb1, p.mW2, p.mb2, e0);
        emb16_v2(x1, p.mW1, p.mb1, p.mW2, p.mb2, e1);
        lg0 = att_logit_v2(e0, qk, p.ma_Wr, p.ma_V);
        lg1 = att_logit_v2(e1, qk, p.ma_Wr, p.ma_V);
    }

    float l = (v ? __expf(lg0.x) : 0.0f) + (v ? __expf(lg0.y) : 0.0f)
            + (v ? __expf(lg1.x) : 0.0f) + (v ? __expf(lg1.y) : 0.0f);
    float am0 = v ? lg0.x : -3.4e38f;
    float am1 = v ? lg0.y : -3.4e38f;
    float am2 = v ? lg1.x : -3.4e38f;
    float am3 = v ? lg1.y : -3.4e38f;
    float best = am0; int bi = r0;
    if (am1 > best) { best = am1; bi = r0 + 1; }
    if (am2 > best) { best = am2; bi = r0 + 2; }
    if (am3 > best) { best = am3; bi = r0 + 3; }

    l = wave_reduce_sum(l);
    wave_reduce_argmax(best, bi);
    __shared__ float rl[4], rv[4];
    __shared__ int ri[4];
    int w = threadIdx.x >> 6, ln = threadIdx.x & 63;
    if (ln == 0) { rl[w] = l; rv[w] = best; ri[w] = bi; }
    __syncthreads();
    if (threadIdx.x == 0) {
        float L = rl[0] + rl[1] + rl[2] + rl[3];
        float vv = rv[0]; int i = ri[0];
#pragma unroll
        for (int k = 1; k < 4; ++k)
            if (rv[k] > vv || (rv[k] == vv && ri[k] < i)) { vv = rv[k]; i = ri[k]; }
        p.S[P2V + blockIdx.x] = vv;
        p.S[P2I + blockIdx.x] = (float)i;
        p.S[P2L + blockIdx.x] = L;
    }
}

// ---------------------------------------------------------------------------
// C4: final combine -> outputs [sel_j, sel_m, logpas] as float32
// ---------------------------------------------------------------------------
__global__ __launch_bounds__(BLK) void k_combine4(Params p) {
    float v = -3.4e38f; int vi = 0x7fffffff; float l = 0.0f;
    for (int i = threadIdx.x; i < GB_M; i += BLK) {
        float pv = p.S[P2V + i];
        int pi = (int)p.S[P2I + i];
        if (pv > v || (pv == v && pi < vi)) { v = pv; vi = pi; }
        l += p.S[P2L + i];
    }
    l = block_sum(l);
    block_argmax(v, vi);
    if (threadIdx.x == 0) {
        p.out[0] = p.S[S_SELJ];
        p.out[1] = (float)vi;
        p.out[2] = p.S[S_LOGPJ] + (v - logf(l));
    }
}

// ---------------------------------------------------------------------------
extern "C" void kernel_launch(void* const* d_in, const int* in_sizes, int n_in,
                              void* d_out, int out_size, void* d_ws, size_t ws_size,
                              hipStream_t stream) {
    Params p;
    p.jobs     = (const float*)d_in[0];
    p.machines = (const float*)d_in[1];
    p.mask     = (const int*)d_in[2];
    p.jW1 = (const float*)d_in[3];  p.jb1 = (const float*)d_in[4];
    p.jW2 = (const float*)d_in[5];  p.jb2 = (const float*)d_in[6];
    p.mW1 = (const float*)d_in[7];  p.mb1 = (const float*)d_in[8];
    p.mW2 = (const float*)d_in[9];  p.mb2 = (const float*)d_in[10];
    p.aj_Wq = (const float*)d_in[11]; p.aj_bq = (const float*)d_in[12];
    p.aj_Wr = (const float*)d_in[13]; p.aj_V  = (const float*)d_in[14];
    p.am_Wq = (const float*)d_in[15]; p.am_bq = (const float*)d_in[16];
    p.am_Wr = (const float*)d_in[17]; p.am_V  = (const float*)d_in[18];
    p.ja_Wq = (const float*)d_in[19]; p.ja_bq = (const float*)d_in[20];
    p.ja_Wr = (const float*)d_in[21]; p.ja_V  = (const float*)d_in[22];
    p.ma_Wq = (const float*)d_in[23]; p.ma_bq = (const float*)d_in[24];
    p.ma_Wr = (const float*)d_in[25]; p.ma_V  = (const float*)d_in[26];
    p.g1W = (const float*)d_in[27]; p.g1b = (const float*)d_in[28];
    p.g2W = (const float*)d_in[29]; p.g2b = (const float*)d_in[30];
    p.last_j = (const float*)d_in[31];
    p.S = (float*)d_ws;
    p.Ej = (float*)d_ws + E_OFF;
    p.Em = p.Ej + (size_t)GB_J * EBLK;
    p.Wj = p.Ej + (size_t)GB_TOT * EBLK;
    p.Wm = p.Wj + (size_t)GB_J * EBLK;
    p.out = (float*)d_out;

    const size_t need_e    = (E_OFF + (size_t)GB_TOT * EBLK) * sizeof(float);
    const size_t need_full = (E_OFF + 2 * (size_t)GB_TOT * EBLK) * sizeof(float);
    const int tier = (ws_size >= need_full) ? 2 : (ws_size >= need_e ? 1 : 0);

    if (tier == 2) {
        k_emb_g1<2><<<GB_TOT, BLK, 0, stream>>>(p);
        k_combine_g<<<1, BLK, 0, stream>>>(p, 0);
        k_jlogits<2><<<GB_J, BLK, 0, stream>>>(p);
        k_combine2<<<1, BLK, 0, stream>>>(p);
        k_glimpse2<2><<<GB_TOT, BLK, 0, stream>>>(p);
        k_combine_g<<<1, BLK, 0, stream>>>(p, 1);
        k_mlogits<2><<<GB_M, BLK, 0, stream>>>(p);
        k_combine4<<<1, BLK, 0, stream>>>(p);
    } else if (tier == 1) {
        k_emb_g1<1><<<GB_TOT, BLK, 0, stream>>>(p);
        k_combine_g<<<1, BLK, 0, stream>>>(p, 0);
        k_jlogits<1><<<GB_J, BLK, 0, stream>>>(p);
        k_combine2<<<1, BLK, 0, stream>>>(p);
        k_glimpse2<1><<<GB_TOT, BLK, 0, stream>>>(p);
        k_combine_g<<<1, BLK, 0, stream>>>(p, 1);
        k_mlogits<1><<<GB_M, BLK, 0, stream>>>(p);
        k_combine4<<<1, BLK, 0, stream>>>(p);
    } else {
        k_emb_g1<0><<<GB_TOT, BLK, 0, stream>>>(p);
        k_combine_g<<<1, BLK, 0, stream>>>(p, 0);
        k_jlogits<0><<<GB_J, BLK, 0, stream>>>(p);
        k_combine2<<<1, BLK, 0, stream>>>(p);
        k_glimpse2<0><<<GB_TOT, BLK, 0, stream>>>(p);
        k_combine_g<<<1, BLK, 0, stream>>>(p, 1);
        k_mlogits<0><<<GB_M, BLK, 0, stream>>>(p);
        k_combine4<<<1, BLK, 0, stream>>>(p);
    }
}

// Round 14
// 284.496 us; speedup vs baseline: 1.1547x; 1.1050x over previous
//
#include <hip/hip_runtime.h>
#include <cstddef>
#include <cstdint>

// ---------------------------------------------------------------------------
// attention_net_noc: pointer-network decode step.
// R17 = R14 verbatim (282.5 us, session best). Final configuration:
//  - 4 adjacent rows/thread (16 loads in flight; R9->R10 win),
//  - E-cache as feature-pair-interleaved float4 tiles (lane-contiguous),
//  - reduce-scatter block_sum17 (23 DS ops vs 102),
//  - 5-instr fast_tanh, int4 mask load issued before E loads,
//  - separate 1-block combines (kernel boundaries = the only cheap sync).
// Measured dead ends: ticket fences (R8 6x), coop grid barriers (R11 3.2x),
// redundant combine prologues (R12 +23us), A-repack/NT stores (R13 +6us),
// wr-precompute fat/frugal (R15 +46 / R16 +32: producer store-latency cost
// exceeds consumer VALU savings at A's occupancy), E-recompute (R7 +49us),
// bf16 cache (argmax-flip risk). Remaining structure is latency-bound
// serial sweeps; plateau.
// ---------------------------------------------------------------------------

constexpr int NJ = 1000000;
constexpr int NM = 500000;
constexpr float NEGV = -1e8f;

constexpr int BLK = 256;
constexpr int ROWS_PER_BLK = 1024;           // 4 adjacent rows per thread
constexpr int GB_J = (NJ + ROWS_PER_BLK - 1) / ROWS_PER_BLK;   // 977
constexpr int GB_M = (NM + ROWS_PER_BLK - 1) / ROWS_PER_BLK;   // 489
constexpr int GB_TOT = GB_J + GB_M;                             // 1466
constexpr int EBLK = ROWS_PER_BLK * 16;                         // 16384 floats/tile

// ---- workspace layout (float offsets from start of d_ws) ----
constexpr int S_QKJA = 0;    // 16: ja_Wq@g1 + ja_bq
constexpr int S_QK2J = 16;   // 16: aj_Wq@e_js + aj_bq
constexpr int S_QK2M = 32;   // 16: am_Wq@e_js + am_bq
constexpr int S_EJS  = 48;   // 16: E_j[sel_j]
constexpr int S_QKMA = 64;   // 16: ma_Wq@g2 + ma_bq
constexpr int S_LOGPJ = 80;
constexpr int S_SELJ  = 81;  // stored as float (exact, < 2^24)
constexpr int P1J = 128;                       // GB_J*17 glimpse partials (l, s[16])
constexpr int P1M = P1J + GB_J * 17;
constexpr int P2V = P1M + GB_M * 17;           // GB_J argmax vals (mlogits reuses)
constexpr int P2I = P2V + GB_J;
constexpr int P2L = P2I + GB_J;
constexpr size_t E_OFF = 65536;                // float offset of E cache tiles
static_assert(P2L + GB_J <= (int)E_OFF, "partials overflow into E cache");
static_assert(NJ % 4 == 0 && NM % 4 == 0, "4-row packing needs n % 4 == 0");

typedef float v2f __attribute__((ext_vector_type(2)));

struct Params {
    const float *jobs, *machines;
    const int *mask;
    const float *jW1, *jb1, *jW2, *jb2;
    const float *mW1, *mb1, *mW2, *mb2;
    const float *aj_Wq, *aj_bq, *aj_Wr, *aj_V;
    const float *am_Wq, *am_bq, *am_Wr, *am_V;
    const float *ja_Wq, *ja_bq, *ja_Wr, *ja_V;
    const float *ma_Wq, *ma_bq, *ma_Wr, *ma_V;
    const float *g1W, *g1b, *g2W, *g2b, *last_j;
    float *S;        // smalls + partials (in ws)
    float *Ej, *Em;  // embedding cache tiles (in ws; valid only if CACHE)
    float *out;
};

// ---------------------------------------------------------------------------
// device helpers (verified R9-R14)
// ---------------------------------------------------------------------------

__device__ __forceinline__ float fast_tanh(float x) {
    float e = __builtin_amdgcn_exp2f(x * 2.8853900817779268f);  // 2/ln2
    float r = __builtin_amdgcn_rcpf(e + 1.0f);
    return fmaf(-2.0f, r, 1.0f);
}

__device__ __forceinline__ v2f vbc(float a) { v2f r; r.x = a; r.y = a; return r; }

__device__ __forceinline__ v2f vfma(float w, v2f b, v2f c) {
    return __builtin_elementwise_fma(vbc(w), b, c);
}
__device__ __forceinline__ v2f vfma2(v2f a, v2f b, v2f c) {
    return __builtin_elementwise_fma(a, b, c);
}
__device__ __forceinline__ v2f vtanh(v2f a) {
    v2f r; r.x = fast_tanh(a.x); r.y = fast_tanh(a.y); return r;
}

__device__ __forceinline__ void load16(const float* __restrict__ X, size_t r, float (&x)[16]) {
    const float4* p4 = reinterpret_cast<const float4*>(X) + r * 4;
    float4 a = p4[0], b = p4[1], c = p4[2], d = p4[3];
    x[0]=a.x; x[1]=a.y; x[2]=a.z; x[3]=a.w;
    x[4]=b.x; x[5]=b.y; x[6]=b.z; x[7]=b.w;
    x[8]=c.x; x[9]=c.y; x[10]=c.z; x[11]=c.w;
    x[12]=d.x; x[13]=d.y; x[14]=d.z; x[15]=d.w;
}

__device__ __forceinline__ void load16_v2(const float* __restrict__ X, size_t rA, size_t rB,
                                          v2f (&x)[16]) {
    float a[16], b[16];
    load16(X, rA, a);
    load16(X, rB, b);
#pragma unroll
    for (int k = 0; k < 16; ++k) { x[k].x = a[k]; x[k].y = b[k]; }
}

// E-cache tile for 4 rows/thread: [8][2 pairs][256 threads * float4].
__device__ __forceinline__ void ecache_store4(float* __restrict__ Eb, int t,
                                              const v2f (&e0)[16], const v2f (&e1)[16]) {
    float4* p4 = reinterpret_cast<float4*>(Eb);
#pragma unroll
    for (int kp = 0; kp < 8; ++kp) {
        p4[kp * 512 + t]       = make_float4(e0[2*kp].x, e0[2*kp].y, e0[2*kp+1].x, e0[2*kp+1].y);
        p4[kp * 512 + 256 + t] = make_float4(e1[2*kp].x, e1[2*kp].y, e1[2*kp+1].x, e1[2*kp+1].y);
    }
}
__device__ __forceinline__ void ecache_load4(const float* __restrict__ Eb, int t,
                                             v2f (&e0)[16], v2f (&e1)[16]) {
    const float4* p4 = reinterpret_cast<const float4*>(Eb);
#pragma unroll
    for (int kp = 0; kp < 8; ++kp) {
        float4 q0 = p4[kp * 512 + t];
        float4 q1 = p4[kp * 512 + 256 + t];
        e0[2*kp].x = q0.x;   e0[2*kp].y = q0.y;
        e0[2*kp+1].x = q0.z; e0[2*kp+1].y = q0.w;
        e1[2*kp].x = q1.x;   e1[2*kp].y = q1.y;
        e1[2*kp+1].x = q1.z; e1[2*kp+1].y = q1.w;
    }
}

__device__ __forceinline__ void emb16_v2(const v2f (&x)[16],
                                         const float* __restrict__ W1, const float* __restrict__ b1,
                                         const float* __restrict__ W2, const float* __restrict__ b2,
                                         v2f (&e)[16]) {
    v2f h[16];
#pragma unroll
    for (int i = 0; i < 16; ++i) {
        v2f a = vbc(b1[i]);
#pragma unroll
        for (int k = 0; k < 16; ++k) a = vfma(W1[i * 16 + k], x[k], a);
        h[i] = vtanh(a);
    }
#pragma unroll
    for (int i = 0; i < 16; ++i) {
        v2f a = vbc(b2[i]);
#pragma unroll
        for (int k = 0; k < 16; ++k) a = vfma(W2[i * 16 + k], h[k], a);
        e[i] = vtanh(a);
    }
}

__device__ __forceinline__ v2f att_logit_v2(const v2f (&e)[16], const float (&qk)[16],
                                            const float* __restrict__ Wr,
                                            const float* __restrict__ V) {
    v2f acc = vbc(0.0f);
#pragma unroll
    for (int i = 0; i < 16; ++i) {
        v2f r = vbc(qk[i]);
#pragma unroll
        for (int k = 0; k < 16; ++k) r = vfma(Wr[i * 16 + k], e[k], r);
        acc = vfma2(vbc(V[i]), vtanh(r), acc);
    }
    return acc;
}

__device__ __forceinline__ float wave_reduce_sum(float v) {
#pragma unroll
    for (int off = 32; off > 0; off >>= 1) v += __shfl_xor(v, off, 64);
    return v;
}

__device__ __forceinline__ void wave_reduce_argmax(float &v, int &idx) {
#pragma unroll
    for (int off = 32; off > 0; off >>= 1) {
        float ov = __shfl_xor(v, off, 64);
        int oi = __shfl_xor(idx, off, 64);
        if (ov > v || (ov == v && oi < idx)) { v = ov; idx = oi; }
    }
}

__device__ __forceinline__ float block_sum(float v) {
    __shared__ float sm[4];
    v = wave_reduce_sum(v);
    __syncthreads();
    if ((threadIdx.x & 63) == 0) sm[threadIdx.x >> 6] = v;
    __syncthreads();
    return sm[0] + sm[1] + sm[2] + sm[3];
}

__device__ __forceinline__ void block_argmax(float &v, int &i) {
    __shared__ float sv[4];
    __shared__ int si[4];
    wave_reduce_argmax(v, i);
    __syncthreads();
    if ((threadIdx.x & 63) == 0) { sv[threadIdx.x >> 6] = v; si[threadIdx.x >> 6] = i; }
    __syncthreads();
    float bv = sv[0]; int bi = si[0];
#pragma unroll
    for (int k = 1; k < 4; ++k)
        if (sv[k] > bv || (sv[k] == bv && si[k] < bi)) { bv = sv[k]; bi = si[k]; }
    v = bv; i = bi;
}

// Block-reduce (l, s[16]) -> dst[17]. dst[0]=l, dst[1+j]=s[j]. Verified R7-R16.
__device__ __forceinline__ void block_sum17(float l, const float (&s)[16], float* dst) {
    const int lane = threadIdx.x & 63;
    float c[8];
#pragma unroll
    for (int j = 0; j < 8; ++j) {          // xor 1: 16 -> 8
        const bool hi = lane & 1;
        float t = __shfl_xor(hi ? s[j] : s[j + 8], 1, 64);
        c[j] = (hi ? s[j + 8] : s[j]) + t;
    }
    float d[4];
#pragma unroll
    for (int j = 0; j < 4; ++j) {          // xor 2: 8 -> 4
        const bool hi = lane & 2;
        float t = __shfl_xor(hi ? c[j] : c[j + 4], 2, 64);
        d[j] = (hi ? c[j + 4] : c[j]) + t;
    }
    float e2[2];
#pragma unroll
    for (int j = 0; j < 2; ++j) {          // xor 4: 4 -> 2
        const bool hi = lane & 4;
        float t = __shfl_xor(hi ? d[j] : d[j + 2], 4, 64);
        e2[j] = (hi ? d[j + 2] : d[j]) + t;
    }
    float f;
    {                                       // xor 8: 2 -> 1
        const bool hi = lane & 8;
        float t = __shfl_xor(hi ? e2[0] : e2[1], 8, 64);
        f = (hi ? e2[1] : e2[0]) + t;
    }
    f += __shfl_xor(f, 16, 64);             // merge 16-lane groups
    f += __shfl_xor(f, 32, 64);
#pragma unroll
    for (int off = 32; off > 0; off >>= 1) l += __shfl_xor(l, off, 64);

    const int idx = ((lane & 1) << 3) | ((lane & 2) << 1) | ((lane & 4) >> 1) | ((lane & 8) >> 3);
    __shared__ float red[4][17];
    const int w = threadIdx.x >> 6;
    __syncthreads();                        // guard reuse across successive calls
    if (lane < 16) red[w][1 + idx] = f;
    if (lane == 0) red[w][0] = l;
    __syncthreads();
    if (threadIdx.x < 17)
        dst[threadIdx.x] = red[0][threadIdx.x] + red[1][threadIdx.x] + red[2][threadIdx.x] + red[3][threadIdx.x];
}

// weighted sum of 4 rows: s[i] = w01 . e0[i] + w23 . e1[i]
__device__ __forceinline__ void wsum4(const v2f (&e0)[16], const v2f (&e1)[16],
                                      v2f w01, v2f w23, float (&s)[16]) {
#pragma unroll
    for (int i = 0; i < 16; ++i) {
        v2f t = vfma2(w23, e1[i], w01 * e0[i]);
        s[i] = t.x + t.y;
    }
}

// ---------------------------------------------------------------------------
// K1: embeddings (cached to ws if CACHE) + glimpse-1 partial sums. Rows (4t..4t+3).
// blocks [0,GB_J) -> jobs, [GB_J,GB_TOT) -> machines.
// ---------------------------------------------------------------------------
template <bool CACHE>
__global__ __launch_bounds__(BLK) void k_emb_g1(Params p) {
    const bool isJob = blockIdx.x < GB_J;
    const float* X  = isJob ? p.jobs : p.machines;
    const float* W1 = isJob ? p.jW1 : p.mW1;
    const float* b1 = isJob ? p.jb1 : p.mb1;
    const float* W2 = isJob ? p.jW2 : p.mW2;
    const float* b2 = isJob ? p.jb2 : p.mb2;
    const float* Wr = isJob ? p.aj_Wr : p.am_Wr;
    const float* V  = isJob ? p.aj_V  : p.am_V;
    float* E = isJob ? p.Ej : p.Em;
    const int n  = isJob ? NJ : NM;
    const int b0 = isJob ? (int)blockIdx.x : (int)blockIdx.x - GB_J;

    const int r0 = b0 * ROWS_PER_BLK + 4 * (int)threadIdx.x;
    const bool v = r0 < n;
    const size_t a0 = v ? (size_t)r0 : 0;
    const size_t d  = v ? 1 : 0;

    // issue all 16 global loads first (latency overlaps the qk prologue)
    v2f x0[16], x1[16];
    load16_v2(X, a0, a0 + d, x0);
    load16_v2(X, a0 + 2 * d, a0 + 3 * d, x1);

    __shared__ float qks[16];
    if (threadIdx.x < 16) {
        const float* Wq = isJob ? p.aj_Wq : p.am_Wq;
        const float* bq = isJob ? p.aj_bq : p.am_bq;
        const int i = threadIdx.x;
        float a = bq[i];
#pragma unroll
        for (int k = 0; k < 16; ++k) a = fmaf(Wq[i * 16 + k], p.last_j[k], a);
        qks[i] = a;
    }
    __syncthreads();
    float qk[16];
#pragma unroll
    for (int i = 0; i < 16; ++i) qk[i] = qks[i];

    v2f e0[16], e1[16];
    emb16_v2(x0, W1, b1, W2, b2, e0);
    emb16_v2(x1, W1, b1, W2, b2, e1);
    if (CACHE) ecache_store4(E + (size_t)b0 * EBLK, (int)threadIdx.x, e0, e1);
    v2f lg0 = att_logit_v2(e0, qk, Wr, V);
    v2f lg1 = att_logit_v2(e1, qk, Wr, V);
    // |logit| <= sum|V| ~ 0.6 -> exp never overflows; no max-shift needed.
    v2f w01, w23;
    w01.x = v ? __expf(lg0.x) : 0.0f;
    w01.y = v ? __expf(lg0.y) : 0.0f;
    w23.x = v ? __expf(lg1.x) : 0.0f;
    w23.y = v ? __expf(lg1.y) : 0.0f;
    float l = (w01.x + w01.y) + (w23.x + w23.y);
    float s[16];
    wsum4(e0, e1, w01, w23, s);

    block_sum17(l, s, p.S + (isJob ? P1J : P1M) + (size_t)b0 * 17);
}

// ---------------------------------------------------------------------------
// Combine partials -> g (g1 or g2) -> next-stage qk vector. Single block.
// ---------------------------------------------------------------------------
__global__ __launch_bounds__(BLK) void k_combine_g(Params p, int phase) {
    const float* PJ = p.S + P1J;
    const float* PM = p.S + P1M;
    float lJ = 0.0f, lM = 0.0f, sJ[16], sM[16];
#pragma unroll
    for (int c = 0; c < 16; ++c) { sJ[c] = 0.0f; sM[c] = 0.0f; }
    for (int i = threadIdx.x; i < GB_J; i += BLK) {
        lJ += PJ[i * 17];
#pragma unroll
        for (int c = 0; c < 16; ++c) sJ[c] += PJ[i * 17 + 1 + c];
    }
    for (int i = threadIdx.x; i < GB_M; i += BLK) {
        lM += PM[i * 17];
#pragma unroll
        for (int c = 0; c < 16; ++c) sM[c] += PM[i * 17 + 1 + c];
    }
    __shared__ float totJ[17], totM[17];
    block_sum17(lJ, sJ, totJ);
    block_sum17(lM, sM, totM);
    __syncthreads();

    __shared__ float cb[48], gbuf[16];
    if (threadIdx.x < 16) {
        int i = threadIdx.x;
        cb[i]      = phase ? p.S[S_EJS + i] : p.last_j[i];
        cb[16 + i] = totJ[1 + i] / totJ[0];   // softmax-weighted sum / partition
        cb[32 + i] = totM[1 + i] / totM[0];
    }
    __syncthreads();
    const float* gW  = phase ? p.g2W : p.g1W;
    const float* gbv = phase ? p.g2b : p.g1b;
    if (threadIdx.x < 16) {
        int i = threadIdx.x;
        float a = gbv[i];
#pragma unroll
        for (int k = 0; k < 48; ++k) a = fmaf(gW[i * 48 + k], cb[k], a);
        gbuf[i] = fast_tanh(a);
    }
    __syncthreads();
    const float* Wq = phase ? p.ma_Wq : p.ja_Wq;
    const float* bq = phase ? p.ma_bq : p.ja_bq;
    const int off = phase ? S_QKMA : S_QKJA;
    if (threadIdx.x < 16) {
        int i = threadIdx.x;
        float a = bq[i];
#pragma unroll
        for (int k = 0; k < 16; ++k) a = fmaf(Wq[i * 16 + k], gbuf[k], a);
        p.S[off + i] = a;
    }
}

// ---------------------------------------------------------------------------
// K3: job pointer logits -> masked argmax + sum-exp partials. Rows (4t..4t+3).
// Mask load issued BEFORE the E loads (in flight together).
// ---------------------------------------------------------------------------
template <bool CACHE>
__global__ __launch_bounds__(BLK) void k_jlogits(Params p) {
    const int r0 = blockIdx.x * ROWS_PER_BLK + 4 * (int)threadIdx.x;
    const bool v = r0 < NJ;
    const size_t a0 = v ? (size_t)r0 : 0;
    const size_t d  = v ? 1 : 0;

    int4 mq = make_int4(0, 0, 0, 0);
    if (v) mq = *reinterpret_cast<const int4*>(p.mask + r0);   // r0 mult of 4 -> 16B aligned

    v2f e0[16], e1[16];
    if (CACHE) {
        ecache_load4(p.Ej + (size_t)blockIdx.x * EBLK, (int)threadIdx.x, e0, e1);
    } else {
        v2f x0[16], x1[16];
        load16_v2(p.jobs, a0, a0 + d, x0);
        load16_v2(p.jobs, a0 + 2 * d, a0 + 3 * d, x1);
        emb16_v2(x0, p.jW1, p.jb1, p.jW2, p.jb2, e0);
        emb16_v2(x1, p.jW1, p.jb1, p.jW2, p.jb2, e1);
    }
    float qk[16];
#pragma unroll
    for (int i = 0; i < 16; ++i) qk[i] = p.S[S_QKJA + i];

    v2f lg0 = att_logit_v2(e0, qk, p.ja_Wr, p.ja_V);
    v2f lg1 = att_logit_v2(e1, qk, p.ja_Wr, p.ja_V);

    const bool m0 = v && (mq.x != 0);
    const bool m1 = v && (mq.y != 0);
    const bool m2 = v && (mq.z != 0);
    const bool m3 = v && (mq.w != 0);
    float l = (m0 ? __expf(lg0.x) : 0.0f) + (m1 ? __expf(lg0.y) : 0.0f)
            + (m2 ? __expf(lg1.x) : 0.0f) + (m3 ? __expf(lg1.y) : 0.0f);
    float am0 = m0 ? lg0.x : NEGV - 1.0f;  // invalid rows below masked NEG
    float am1 = m1 ? lg0.y : NEGV - 1.0f;
    float am2 = m2 ? lg1.x : NEGV - 1.0f;
    float am3 = m3 ? lg1.y : NEGV - 1.0f;
    float best = am0; int bi = r0;
    if (am1 > best) { best = am1; bi = r0 + 1; }
    if (am2 > best) { best = am2; bi = r0 + 2; }
    if (am3 > best) { best = am3; bi = r0 + 3; }

    l = wave_reduce_sum(l);
    wave_reduce_argmax(best, bi);
    __shared__ float rl[4], rv[4];
    __shared__ int ri[4];
    int w = threadIdx.x >> 6, ln = threadIdx.x & 63;
    if (ln == 0) { rl[w] = l; rv[w] = best; ri[w] = bi; }
    __syncthreads();
    if (threadIdx.x == 0) {
        float L = rl[0] + rl[1] + rl[2] + rl[3];
        float vv = rv[0]; int i = ri[0];
#pragma unroll
        for (int k = 1; k < 4; ++k)
            if (rv[k] > vv || (rv[k] == vv && ri[k] < i)) { vv = rv[k]; i = ri[k]; }
        p.S[P2V + blockIdx.x] = vv;
        p.S[P2I + blockIdx.x] = (float)i;   // exact: i < 2^24
        p.S[P2L + blockIdx.x] = L;
    }
}

// ---------------------------------------------------------------------------
// C2: global argmax over job logits; logp_j; e_js = emb(jobs[sel_j]); qk2j/qk2m
// ---------------------------------------------------------------------------
__global__ __launch_bounds__(BLK) void k_combine2(Params p) {
    float v = -3.4e38f; int vi = 0x7fffffff; float l = 0.0f;
    for (int i = threadIdx.x; i < GB_J; i += BLK) {
        float pv = p.S[P2V + i];
        int pi = (int)p.S[P2I + i];
        if (pv > v || (pv == v && pi < vi)) { v = pv; vi = pi; }
        l += p.S[P2L + i];
    }
    l = block_sum(l);
    block_argmax(v, vi);
    const int sel = vi;

    __shared__ float xb[16], hb[16], eb[16];
    if (threadIdx.x < 16) xb[threadIdx.x] = p.jobs[(size_t)sel * 16 + threadIdx.x];
    __syncthreads();
    if (threadIdx.x < 16) {
        int i = threadIdx.x;
        float a = p.jb1[i];
#pragma unroll
        for (int k = 0; k < 16; ++k) a = fmaf(p.jW1[i * 16 + k], xb[k], a);
        hb[i] = fast_tanh(a);
    }
    __syncthreads();
    if (threadIdx.x < 16) {
        int i = threadIdx.x;
        float a = p.jb2[i];
#pragma unroll
        for (int k = 0; k < 16; ++k) a = fmaf(p.jW2[i * 16 + k], hb[k], a);
        float e = fast_tanh(a);
        eb[i] = e;
        p.S[S_EJS + i] = e;
    }
    __syncthreads();
    if (threadIdx.x < 16) {
        int i = threadIdx.x;
        float a1 = p.aj_bq[i], a2 = p.am_bq[i];
#pragma unroll
        for (int k = 0; k < 16; ++k) {
            a1 = fmaf(p.aj_Wq[i * 16 + k], eb[k], a1);
            a2 = fmaf(p.am_Wq[i * 16 + k], eb[k], a2);
        }
        p.S[S_QK2J + i] = a1;
        p.S[S_QK2M + i] = a2;
    }
    if (threadIdx.x == 0) {
        p.S[S_LOGPJ] = v - logf(l);     // log_softmax at the argmax
        p.S[S_SELJ] = (float)sel;
    }
}

// ---------------------------------------------------------------------------
// K4: glimpse-2 over jobs (aj_*) and machines (am_*), query e_js. Rows (4t..4t+3).
// Writes partials into the (already consumed) P1 buffers.
// ---------------------------------------------------------------------------
template <bool CACHE>
__global__ __launch_bounds__(BLK) void k_glimpse2(Params p) {
    const bool isJob = blockIdx.x < GB_J;
    const float* Wr = isJob ? p.aj_Wr : p.am_Wr;
    const float* V  = isJob ? p.aj_V  : p.am_V;
    const float* E  = isJob ? p.Ej : p.Em;
    const float* X  = isJob ? p.jobs : p.machines;
    const float* W1 = isJob ? p.jW1 : p.mW1;
    const float* b1 = isJob ? p.jb1 : p.mb1;
    const float* W2 = isJob ? p.jW2 : p.mW2;
    const float* b2 = isJob ? p.jb2 : p.mb2;
    const int n  = isJob ? NJ : NM;
    const int b0 = isJob ? (int)blockIdx.x : (int)blockIdx.x - GB_J;
    const int qoff = isJob ? S_QK2J : S_QK2M;

    const int r0 = b0 * ROWS_PER_BLK + 4 * (int)threadIdx.x;
    const bool v = r0 < n;
    const size_t a0 = v ? (size_t)r0 : 0;
    const size_t d  = v ? 1 : 0;

    v2f e0[16], e1[16];
    if (CACHE) {
        ecache_load4(E + (size_t)b0 * EBLK, (int)threadIdx.x, e0, e1);
    } else {
        v2f x0[16], x1[16];
        load16_v2(X, a0, a0 + d, x0);
        load16_v2(X, a0 + 2 * d, a0 + 3 * d, x1);
        emb16_v2(x0, W1, b1, W2, b2, e0);
        emb16_v2(x1, W1, b1, W2, b2, e1);
    }
    float qk[16];
#pragma unroll
    for (int i = 0; i < 16; ++i) qk[i] = p.S[qoff + i];

    v2f lg0 = att_logit_v2(e0, qk, Wr, V);
    v2f lg1 = att_logit_v2(e1, qk, Wr, V);
    v2f w01, w23;
    w01.x = v ? __expf(lg0.x) : 0.0f;
    w01.y = v ? __expf(lg0.y) : 0.0f;
    w23.x = v ? __expf(lg1.x) : 0.0f;
    w23.y = v ? __expf(lg1.y) : 0.0f;
    float l = (w01.x + w01.y) + (w23.x + w23.y);
    float s[16];
    wsum4(e0, e1, w01, w23, s);

    block_sum17(l, s, p.S + (isJob ? P1J : P1M) + (size_t)b0 * 17);
}

// ---------------------------------------------------------------------------
// K5: machine logits -> argmax + sum-exp partials. Rows (4t..4t+3).
// Writes into the (already consumed) P2 buffers.
// ---------------------------------------------------------------------------
template <bool CACHE>
__global__ __launch_bounds__(BLK) void k_mlogits(Params p) {
    const int r0 = blockIdx.x * ROWS_PER_BLK + 4 * (int)threadIdx.x;
    const bool v = r0 < NM;
    const size_t a0 = v ? (size_t)r0 : 0;
    const size_t d  = v ? 1 : 0;

    v2f e0[16], e1[16];
    if (CACHE) {
        ecache_load4(p.Em + (size_t)blockIdx.x * EBLK, (int)threadIdx.x, e0, e1);
    } else {
        v2f x0[16], x1[16];
        load16_v2(p.machines, a0, a0 + d, x0);
        load16_v2(p.machines, a0 + 2 * d, a0 + 3 * d, x1);
        emb16_v2(x0, p.mW1, p.mb1, p.mW2, p.mb2, e0);
        emb16_v2(x1, p.mW1, p.mb1, p.mW2, p.mb2, e1);
    }
    float qk[16];
#pragma unroll
    for (int i = 0; i < 16; ++i) qk[i] = p.S[S_QKMA + i];

    v2f lg0 = att_logit_v2(e0, qk, p.ma_Wr, p.ma_V);
    v2f lg1 = att_logit_v2(e1, qk, p.ma_Wr, p.ma_V);
    float l = (v ? __expf(lg0.x) : 0.0f) + (v ? __expf(lg0.y) : 0.0f)
            + (v ? __expf(lg1.x) : 0.0f) + (v ? __expf(lg1.y) : 0.0f);
    float am0 = v ? lg0.x : -3.4e38f;
    float am1 = v ? lg0.y : -3.4e38f;
    float am2 = v ? lg1.x : -3.4e38f;
    float am3 = v ? lg1.y : -3.4e38f;
    float best = am0; int bi = r0;
    if (am1 > best) { best = am1; bi = r0 + 1; }
    if (am2 > best) { best = am2; bi = r0 + 2; }
    if (am3 > best) { best = am3; bi = r0 + 3; }

    l = wave_reduce_sum(l);
    wave_reduce_argmax(best, bi);
    __shared__ float rl[4], rv[4];
    __shared__ int ri[4];
    int w = threadIdx.x >> 6, ln = threadIdx.x & 63;
    if (ln == 0) { rl[w] = l; rv[w] = best; ri[w] = bi; }
    __syncthreads();
    if (threadIdx.x == 0) {
        float L = rl[0] + rl[1] + rl[2] + rl[3];
        float vv = rv[0]; int i = ri[0];
#pragma unroll
        for (int k = 1; k < 4; ++k)
            if (rv[k] > vv || (rv[k] == vv && ri[k] < i)) { vv = rv[k]; i = ri[k]; }
        p.S[P2V + blockIdx.x] = vv;
        p.S[P2I + blockIdx.x] = (float)i;
        p.S[P2L + blockIdx.x] = L;
    }
}

// ---------------------------------------------------------------------------
// C4: final combine -> outputs [sel_j, sel_m, logpas] as float32
// ---------------------------------------------------------------------------
__global__ __launch_bounds__(BLK) void k_combine4(Params p) {
    float v = -3.4e38f; int vi = 0x7fffffff; float l = 0.0f;
    for (int i = threadIdx.x; i < GB_M; i += BLK) {
        float pv = p.S[P2V + i];
        int pi = (int)p.S[P2I + i];
        if (pv > v || (pv == v && pi < vi)) { v = pv; vi = pi; }
        l += p.S[P2L + i];
    }
    l = block_sum(l);
    block_argmax(v, vi);
    if (threadIdx.x == 0) {
        p.out[0] = p.S[S_SELJ];
        p.out[1] = (float)vi;
        p.out[2] = p.S[S_LOGPJ] + (v - logf(l));
    }
}

// ---------------------------------------------------------------------------
extern "C" void kernel_launch(void* const* d_in, const int* in_sizes, int n_in,
                              void* d_out, int out_size, void* d_ws, size_t ws_size,
                              hipStream_t stream) {
    Params p;
    p.jobs     = (const float*)d_in[0];
    p.machines = (const float*)d_in[1];
    p.mask     = (const int*)d_in[2];
    p.jW1 = (const float*)d_in[3];  p.jb1 = (const float*)d_in[4];
    p.jW2 = (const float*)d_in[5];  p.jb2 = (const float*)d_in[6];
    p.mW1 = (const float*)d_in[7];  p.mb1 = (const float*)d_in[8];
    p.mW2 = (const float*)d_in[9];  p.mb2 = (const float*)d_in[10];
    p.aj_Wq = (const float*)d_in[11]; p.aj_bq = (const float*)d_in[12];
    p.aj_Wr = (const float*)d_in[13]; p.aj_V  = (const float*)d_in[14];
    p.am_Wq = (const float*)d_in[15]; p.am_bq = (const float*)d_in[16];
    p.am_Wr = (const float*)d_in[17]; p.am_V  = (const float*)d_in[18];
    p.ja_Wq = (const float*)d_in[19]; p.ja_bq = (const float*)d_in[20];
    p.ja_Wr = (const float*)d_in[21]; p.ja_V  = (const float*)d_in[22];
    p.ma_Wq = (const float*)d_in[23]; p.ma_bq = (const float*)d_in[24];
    p.ma_Wr = (const float*)d_in[25]; p.ma_V  = (const float*)d_in[26];
    p.g1W = (const float*)d_in[27]; p.g1b = (const float*)d_in[28];
    p.g2W = (const float*)d_in[29]; p.g2b = (const float*)d_in[30];
    p.last_j = (const float*)d_in[31];
    p.S = (float*)d_ws;
    p.Ej = (float*)d_ws + E_OFF;
    p.Em = p.Ej + (size_t)GB_J * EBLK;
    p.out = (float*)d_out;

    const size_t needed = (E_OFF + (size_t)GB_TOT * EBLK) * sizeof(float);
    const bool cache = ws_size >= needed;

    if (cache) {
        k_emb_g1<true><<<GB_TOT, BLK, 0, stream>>>(p);
        k_combine_g<<<1, BLK, 0, stream>>>(p, 0);
        k_jlogits<true><<<GB_J, BLK, 0, stream>>>(p);
        k_combine2<<<1, BLK, 0, stream>>>(p);
        k_glimpse2<true><<<GB_TOT, BLK, 0, stream>>>(p);
        k_combine_g<<<1, BLK, 0, stream>>>(p, 1);
        k_mlogits<true><<<GB_M, BLK, 0, stream>>>(p);
        k_combine4<<<1, BLK, 0, stream>>>(p);
    } else {
        k_emb_g1<false><<<GB_TOT, BLK, 0, stream>>>(p);
        k_combine_g<<<1, BLK, 0, stream>>>(p, 0);
        k_jlogits<false><<<GB_J, BLK, 0, stream>>>(p);
        k_combine2<<<1, BLK, 0, stream>>>(p);
        k_glimpse2<false><<<GB_TOT, BLK, 0, stream>>>(p);
        k_combine_g<<<1, BLK, 0, stream>>>(p, 1);
        k_mlogits<false><<<GB_M, BLK, 0, stream>>>(p);
        k_combine4<<<1, BLK, 0, stream>>>(p);
    }
}